// Round 13
// baseline (1377.583 us; speedup 1.0000x reference)
//
#include <hip/hip_runtime.h>

// ---------------------------------------------------------------------------
// M3GNet forward. N=8000, E=200000, A=400000, NG=100, FD=128.
// R29 = R28 + Phase 0 software-pipelined with double-buffered msg slab:
// batch k's MFMA stores go to slab[k&1]; batch k-1's flush (pure VALU on
// registers) runs while those stores are in flight; ONE lgkm drain per batch
// (WAR drain eliminated — alternating slabs; slab X's reads at iter k are
// ordered before iter k+2's stores by iter k+1's drain). LDS +8704 B ->
// 26368 B/block = 6 blocks/CU (>= achieved 5.8, R28 showed occupancy is not
// LDS-capped). Register high-water ~unchanged (gvv+mvv already co-live).
// ---------------------------------------------------------------------------

typedef short short8 __attribute__((ext_vector_type(8)));
typedef float f32x4v __attribute__((ext_vector_type(4)));
typedef __bf16 bf16x2_t __attribute__((ext_vector_type(2)));

__device__ __forceinline__ float sigmoidf_(float x) { return 1.0f / (1.0f + __expf(-x)); }
__device__ __forceinline__ float swishf_(float x) { return x * sigmoidf_(x); }

// packed bf16 convert: dst.lo = bf16(a), dst.hi = bf16(b). RNE.
__device__ __forceinline__ unsigned int pk2(float a, float b) {
    bf16x2_t v = {(__bf16)a, (__bf16)b};
    return __builtin_bit_cast(unsigned int, v);
}
__device__ __forceinline__ unsigned short f2bf(float x) {
    return __builtin_bit_cast(unsigned short, (__bf16)x);
}
__device__ __forceinline__ float bf2f(unsigned short u) {
    return __uint_as_float(((unsigned int)u) << 16);
}
__device__ __forceinline__ float blo(unsigned int u) { return __uint_as_float(u << 16); }
__device__ __forceinline__ float bhi(unsigned int u) { return __uint_as_float(u & 0xffff0000u); }
__device__ __forceinline__ unsigned int addbf2(unsigned int a, unsigned int b) {
    return pk2(blo(a) + blo(b), bhi(a) + bhi(b));
}

__device__ __forceinline__ f32x4v mfma_bf16(short8 a, short8 b, f32x4v c) {
    return __builtin_amdgcn_mfma_f32_16x16x32_bf16(a, b, c, 0, 0, 0);
}

__device__ __forceinline__ float4 f4add(float4 a, float4 b) {
    return make_float4(a.x + b.x, a.y + b.y, a.z + b.z, a.w + b.w);
}
__device__ __forceinline__ float4 f4swish(float4 a) {
    return make_float4(swishf_(a.x), swishf_(a.y), swishf_(a.z), swishf_(a.w));
}
__device__ __forceinline__ float getc(const float4& v, int i) {
    return i == 0 ? v.x : (i == 1 ? v.y : (i == 2 ? v.z : v.w));
}

#define FMA4(J, A) \
    acc[J].x = fmaf(A, bv.x, acc[J].x); acc[J].y = fmaf(A, bv.y, acc[J].y); \
    acc[J].z = fmaf(A, bv.z, acc[J].z); acc[J].w = fmaf(A, bv.w, acc[J].w)

template <int S>
__device__ __forceinline__ void gemm32f(const float* As, const float* __restrict__ B,
                                        int tm, int f0, float4 acc[4]) {
#pragma unroll 4
    for (int k = 0; k < 128; ++k) {
        const float4 a0 = *(const float4*)(As + k * S + (tm << 2));
        const float4 bv = *(const float4*)(B + (k << 7) + f0);
        FMA4(0, a0.x); FMA4(1, a0.y); FMA4(2, a0.z); FMA4(3, a0.w);
    }
}

// ---------------------------------------------------------------------------
__global__ void k_offsets(const int* __restrict__ tnb, const int* __restrict__ tna,
                          int NG, int* __restrict__ boff, int* __restrict__ acum) {
    if (threadIdx.x == 0 && blockIdx.x == 0) {
        int ab = 0, aa = 0;
        for (int g = 0; g < NG; ++g) {
            boff[g] = ab;
            ab += tnb[g];
            aa += tna[g];
            acum[g] = aa;
        }
    }
}

__global__ void k_angle_setup(const int* __restrict__ tb, const float* __restrict__ rnorm,
                              const float* __restrict__ cosang, const int* __restrict__ ei,
                              int E, int A, int NG,
                              const int* __restrict__ boff, const int* __restrict__ acum,
                              unsigned short* __restrict__ ang,
                              int* __restrict__ kat, int* __restrict__ iij,
                              int* __restrict__ cnt) {
    const int a = blockIdx.x * 256 + threadIdx.x;
    if (a >= A) return;
    int lo = 0, hi = NG - 1;
    while (lo < hi) {
        const int mid = (lo + hi) >> 1;
        if (a < acum[mid]) hi = mid; else lo = mid + 1;
    }
    const int off = boff[lo];
    iij[a] = tb[2 * a] + off;
    kat[a] = ei[(size_t)E + tb[2 * a + 1] + off];
    atomicAdd(&cnt[tb[2 * a] + off], 1);

    const float r = rnorm[a], c = cosang[a];
    const float rinv = 1.0f / r;
    const float x = r * 0.25f;
    const float fc = 1.0f + x * x * x * (-10.0f + x * (15.0f - 6.0f * x));
    const float fc2 = fc * fc;
    const float p2 = 1.5f * c * c - 0.5f;
    const float p3 = 2.5f * c * c * c - 1.5f * c;
    union { unsigned int ui[8]; uint4 v[2]; } pkk;
#pragma unroll
    for (int n = 0; n < 4; ++n) {
        const float rad = __sinf(r * (float)(n + 1) * 0.7853981633974483f) * rinv * fc2;
        pkk.ui[n * 2 + 0] = pk2(rad, rad * c);
        pkk.ui[n * 2 + 1] = pk2(rad * p2, rad * p3);
    }
    uint4* ap = (uint4*)(ang + (size_t)a * 16);
    ap[0] = pkk.v[0];
    ap[1] = pkk.v[1];
}

__global__ void k_scan1(const int* __restrict__ cnt, int* __restrict__ start,
                        int* __restrict__ bsum, int n) {
    __shared__ int sh[256];
    const int t = threadIdx.x;
    const int base = blockIdx.x * 2048 + t * 8;
    int v[8], s = 0;
#pragma unroll
    for (int i = 0; i < 8; ++i) { v[i] = (base + i < n) ? cnt[base + i] : 0; s += v[i]; }
    sh[t] = s;
    __syncthreads();
    for (int off = 1; off < 256; off <<= 1) {
        int x = (t >= off) ? sh[t - off] : 0;
        __syncthreads();
        sh[t] += x;
        __syncthreads();
    }
    if (t == 255) bsum[blockIdx.x] = sh[255];
    int run = sh[t] - s;
#pragma unroll
    for (int i = 0; i < 8; ++i) { if (base + i < n) start[base + i] = run; run += v[i]; }
}

__global__ void k_scan2(int* __restrict__ bsum, int nb) {
    __shared__ int sh[256];
    const int t = threadIdx.x;
    int v = (t < nb) ? bsum[t] : 0;
    sh[t] = v;
    __syncthreads();
    for (int off = 1; off < 256; off <<= 1) {
        int x = (t >= off) ? sh[t - off] : 0;
        __syncthreads();
        sh[t] += x;
        __syncthreads();
    }
    if (t < nb) bsum[t] = sh[t] - v;
}

__global__ void k_scan3(int* __restrict__ start, const int* __restrict__ bsum, int n) {
    const int i = blockIdx.x * 256 + threadIdx.x;
    if (i < n) start[i] += bsum[i >> 11];
}

__global__ void k_scatter(const unsigned short* __restrict__ ang,
                          const int* __restrict__ kat, const int* __restrict__ iij,
                          const int* __restrict__ start, int* __restrict__ fill,
                          unsigned short* __restrict__ angS, int* __restrict__ katS, int A) {
    const int a = blockIdx.x * 256 + threadIdx.x;
    if (a >= A) return;
    const int ij = iij[a];
    const int pos = start[ij] + atomicAdd(&fill[ij], 1);
    const uint4* src = (const uint4*)(ang + (size_t)a * 16);
    uint4* dst = (uint4*)(angS + (size_t)pos * 16);
    dst[0] = src[0];
    dst[1] = src[1];
    katS[pos] = kat[a];
}

__global__ void k_scatter_recv(const int* __restrict__ ei, int E,
                               const int* __restrict__ startR, int* __restrict__ fillR,
                               int* __restrict__ epos) {
    const int e = blockIdx.x * 256 + threadIdx.x;
    if (e < E) {
        const int r = ei[(size_t)E + e];
        epos[e] = startR[r] + atomicAdd(&fillR[r], 1);
    }
}

// pack 32 weight matrices into MFMA B-frag layout (bf16).
// mat = b*8 + {0:Wg, 1:We1a, 2:We1b, 3:Wa1a, 4:Wa1b, 5:Wtb, 6:We1c, 7:Wa1c}
__global__ void k_pack(const float* __restrict__ Wg, const float* __restrict__ Wtb,
                       const float* __restrict__ We1, const float* __restrict__ Wa1,
                       unsigned short* __restrict__ Bpk) {
    const int gid = blockIdx.x * 256 + threadIdx.x;  // 0..65535
    const int mat = gid >> 11;
    const int t2 = gid & 2047;
    const int b = mat >> 3, which = mat & 7;
    const float* W;
    switch (which) {
        case 0: W = Wg + (size_t)b * 16384; break;
        case 1: W = We1 + (size_t)b * 49152; break;
        case 2: W = We1 + (size_t)b * 49152 + 16384; break;
        case 3: W = Wa1 + (size_t)b * 49152; break;
        case 4: W = Wa1 + (size_t)b * 49152 + 16384; break;
        case 5: W = Wtb + (size_t)b * 16384; break;
        case 6: W = We1 + (size_t)b * 49152 + 32768; break;
        default: W = Wa1 + (size_t)b * 49152 + 32768; break;
    }
    const int kc = t2 >> 9, nt = (t2 >> 6) & 7, lane = t2 & 63;
    const int q = lane >> 4, cc = lane & 15;
    const int col = nt * 16 + cc;
    union { unsigned short us[8]; uint4 v; } pk;
#pragma unroll
    for (int j = 0; j < 8; ++j)
        pk.us[j] = f2bf(W[(size_t)(kc * 32 + q * 8 + j) * 128 + col]);
    *(uint4*)(Bpk + (size_t)mat * 16384 + (size_t)((kc * 8 + nt) * 64 + lane) * 8) = pk.v;
}

// pack small-K matrices into MFMA B-frag layout (K padded to 32 with 0).
// m = type*4 + b; type 0: Wang (K=16), type 1: We0 (K=5), type 2: Wa0 (K=5).
__global__ void k_pack_s(const float* __restrict__ Wang, const float* __restrict__ We0g,
                         const float* __restrict__ Wa0g, unsigned short* __restrict__ Spk) {
    const int gid = blockIdx.x * 64 + threadIdx.x;  // 12 mats * 512 lanes
    const int m = gid >> 9;
    const int nt = (gid >> 6) & 7, lane = gid & 63;
    const int b = m & 3, type = m >> 2;
    const int q = lane >> 4, cc = lane & 15;
    const int col = nt * 16 + cc;
    const float* W;
    int K;
    if (type == 0)      { W = Wang + (size_t)b * 2048; K = 16; }
    else if (type == 1) { W = We0g + (size_t)b * 640;  K = 5;  }
    else                { W = Wa0g + (size_t)b * 640;  K = 5;  }
    union { unsigned short us[8]; uint4 v; } pk;
#pragma unroll
    for (int j = 0; j < 8; ++j) {
        const int k = q * 8 + j;
        pk.us[j] = (k < K) ? f2bf(W[(size_t)k * 128 + col]) : (unsigned short)0;
    }
    *(uint4*)(Spk + (size_t)m * 4096 + (size_t)(nt * 64 + lane) * 8) = pk.v;
}

// e init, slot-major layout: ePq[(strip*16 + s)*64 + lane], s = nt*2 + half.
// Also folds the recv-degree histogram and writes ef0q (A-frag-ready bf16x8:
// 5 rbf values + 3 zeros per edge).
__global__ void k_edge_init(const float* __restrict__ dist, const float* __restrict__ Wenc,
                            const float* __restrict__ benc,
                            const int* __restrict__ ei, int E, int* __restrict__ cntR,
                            unsigned int* __restrict__ ePq,
                            unsigned int* __restrict__ ef0q) {
    __shared__ float sarr[16][5];
    const int s = blockIdx.x, t = threadIdx.x;
    if (t < 16) {
        const float r = dist[s * 16 + t];
        const float rinv = 1.0f / r;
        float vv[5];
#pragma unroll
        for (int n = 0; n < 5; ++n) {
            vv[n] = 0.6324555320336759f * __sinf(r * (float)(n + 1) * 0.6283185307179586f) * rinv;
            sarr[t][n] = vv[n];
        }
        uint4 pq;
        pq.x = pk2(vv[0], vv[1]);
        pq.y = pk2(vv[2], vv[3]);
        pq.z = pk2(vv[4], 0.0f);
        pq.w = 0u;
        *(uint4*)(ef0q + (size_t)(s * 16 + t) * 4) = pq;
        atomicAdd(&cntR[ei[(size_t)E + s * 16 + t]], 1);
    }
    __syncthreads();
    const int lane = t >> 3, nt = t & 7;
    const int q = lane >> 4;
    const int f = nt * 16 + (lane & 15);
    float wv[5];
#pragma unroll
    for (int n = 0; n < 5; ++n) wv[n] = Wenc[n * 128 + f];
    const float bz = benc[f];
    float o[4];
#pragma unroll
    for (int r = 0; r < 4; ++r) {
        const int m = q * 4 + r;
        float acc = bz;
#pragma unroll
        for (int n = 0; n < 5; ++n) acc = fmaf(sarr[m][n], wv[n], acc);
        o[r] = swishf_(acc);
    }
    unsigned int* epB = ePq + (size_t)s * 1024;
    epB[(nt * 2) * 64 + lane] = pk2(o[0], o[1]);
    epB[(nt * 2 + 1) * 64 + lane] = pk2(o[2], o[3]);
}

// atom init: v fp32 + vq bf16-packed (lane j holds features 2j,2j+1)
__global__ void k_atom_init(const int* __restrict__ an, const float* __restrict__ emb,
                            float* __restrict__ v, unsigned int* __restrict__ vq, int N) {
    const size_t gid = (size_t)blockIdx.x * 256 + threadIdx.x;
    if (gid >= (size_t)N * 64) return;
    const int a = (int)(gid >> 6), j = (int)(gid & 63);
    const float2 e = *(const float2*)(emb + (size_t)an[a] * 128 + 2 * j);
    *(float2*)(v + (size_t)a * 128 + 2 * j) = e;
    vq[gid] = pk2(e.x, e.y);
}

// ---------------------------------------------------------------------------
// MFMA per-atom GEMMs: 64 atoms/block, wave w owns atoms 16w..16w+15.
// blockIdx.y = g selects the matrix (625 blocks/dispatch keeps all CUs busy).
__global__ void __launch_bounds__(256, 4) k_atom_pre(
    const unsigned int* __restrict__ vq,
    const unsigned short* __restrict__ Bpk5, const float* __restrict__ bg,
    unsigned int* __restrict__ Gq, unsigned int* __restrict__ Pe1q,
    unsigned int* __restrict__ Pe2q,
    unsigned int* __restrict__ Pa1q, unsigned int* __restrict__ Pa2q) {
    __shared__ __align__(16) unsigned short At[64 * 136];
    unsigned int* At32 = (unsigned int*)At;
    const int t = threadIdx.x;
    const int w = t >> 6, l = t & 63;
    const int q = l >> 4, c = l & 15;
    const int g = blockIdx.y;
    const int abase = blockIdx.x * 64 + 16 * w;

    const unsigned short* vh = (const unsigned short*)vq;
    short8 af[4];
#pragma unroll
    for (int kc = 0; kc < 4; ++kc)
        af[kc] = *(const short8*)(vh + (size_t)(abase + c) * 128 + kc * 32 + q * 8);

    const short8* Bp = (const short8*)(Bpk5 + (size_t)g * 16384);
    const f32x4v zz = {0.0f, 0.0f, 0.0f, 0.0f};
    f32x4v acc[8];
#pragma unroll
    for (int nt = 0; nt < 8; ++nt) acc[nt] = zz;
#pragma unroll
    for (int nt = 0; nt < 8; ++nt)
#pragma unroll
        for (int kc = 0; kc < 4; ++kc)
            acc[nt] = mfma_bf16(af[kc], Bp[(kc * 8 + nt) * 64 + l], acc[nt]);

    unsigned int* OUT = (g == 0) ? Gq : (g == 1) ? Pe1q : (g == 2) ? Pe2q
                      : (g == 3) ? Pa1q : Pa2q;
#pragma unroll
    for (int nt = 0; nt < 8; ++nt) {
        const int fo = nt * 16 + c;
        if (g == 0) {
            const float bz = bg[fo];
#pragma unroll
            for (int r = 0; r < 4; ++r)
                At[(16 * w + q * 4 + r) * 136 + fo] = f2bf(sigmoidf_(acc[nt][r] + bz));
        } else {
#pragma unroll
            for (int r = 0; r < 4; ++r)
                At[(16 * w + q * 4 + r) * 136 + fo] = f2bf(acc[nt][r]);
        }
    }
#pragma unroll
    for (int j = 0; j < 16; ++j)
        OUT[(size_t)(abase + j) * 64 + l] = At32[(16 * w + j) * 68 + l];
}

// ---------------------------------------------------------------------------
// Fused per-edge kernel: Phase 0 (MFMA angle batches, software-pipelined with
// double-buffered msg slab) + 3 MFMA GEMMs (two nt-halves, acc[4]).
// 128 threads / 2 waves / 32 edges per block. All LDS state wave-private ->
// NO cross-wave barrier. Type-punned LDS RAW seams ordered by lgkmcnt(0)+
// sched_barrier fences (R17 lesson). sc factors via MFMA (R27).
__global__ void __launch_bounds__(128, 4) k_edge(
    const unsigned short* __restrict__ angBS, const int* __restrict__ katS,
    const int* __restrict__ startA, const int* __restrict__ cntA,
    const unsigned int* __restrict__ Gq, const unsigned short* __restrict__ Wangpk,
    const unsigned int* __restrict__ ef0q,
    unsigned int* __restrict__ ePq, const int* __restrict__ ei, int E,
    const unsigned int* __restrict__ Pe1q, const unsigned int* __restrict__ Pe2q,
    const unsigned int* __restrict__ Pa1q, const unsigned int* __restrict__ Pa2q,
    const int* __restrict__ epos,
    const unsigned short* __restrict__ Bpk3,
    const float* __restrict__ btb, const float* __restrict__ be1,
    const unsigned short* __restrict__ We0pk, const float* __restrict__ ba1,
    const unsigned short* __restrict__ Wa0pk, unsigned int* __restrict__ mPq) {
    __shared__ __align__(16) unsigned short At[32 * 136];
    __shared__ __align__(16) unsigned short sPh[32 * 136];
    __shared__ __align__(16) unsigned short sMsg[32 * 136];
    __shared__ int sA0[32], sAn[32];
    unsigned int* At32 = (unsigned int*)At;
    unsigned int* sP32 = (unsigned int*)sPh;

    const int t = threadIdx.x;
    const int w = t >> 6, l = t & 63;
    const int q = l >> 4, c = l & 15;
    const int g4 = l >> 4, l16 = l & 15;
    const size_t base = (size_t)blockIdx.x * 32;
    const int wbase = (int)base + 16 * w;
    const f32x4v zz = {0.0f, 0.0f, 0.0f, 0.0f};

    if (l < 16) {
        sA0[16 * w + l] = startA[wbase + l];
        sAn[16 * w + l] = cntA[wbase + l];
    }

    // prefetch this lane's edge-index rows (feeds STAGE_SP gather addresses)
    int eiS[4], eiR[4];
#pragma unroll
    for (int i = 0; i < 4; ++i) {
        eiS[i] = ei[wbase + i * 4 + g4];
        eiR[i] = ei[(size_t)E + wbase + i * 4 + g4];
    }

    // A-frag of ef0 (row = edge wbase+c, K=5 padded): q==0 lanes hold the 5
    // bf16 rbf values (+3 zeros); q>=1 lanes are zero.
    short8 afE = {0, 0, 0, 0, 0, 0, 0, 0};
    if (q == 0)
        afE = *(const short8*)((const unsigned short*)ef0q + (size_t)(wbase + c) * 8);

#define STAGE_SP(P1, P2)                                                         \
    _Pragma("unroll") for (int i = 0; i < 4; ++i) {                              \
        const int j = i * 4 + g4;                                                \
        const uint4 u1 = *(const uint4*)((P1) + (size_t)eiS[i] * 64 + l16 * 4);  \
        const uint4 u2 = *(const uint4*)((P2) + (size_t)eiR[i] * 64 + l16 * 4);  \
        uint4 o;                                                                 \
        o.x = addbf2(u1.x, u2.x); o.y = addbf2(u1.y, u2.y);                      \
        o.z = addbf2(u1.z, u2.z); o.w = addbf2(u1.w, u2.w);                      \
        *(uint4*)(sP32 + (16 * w + j) * 68 + l16 * 4) = o;                       \
    }

    unsigned int* epB = ePq + (size_t)(blockIdx.x * 2 + w) * 1024;  // slot-major

    // ---- Phase 0: software-pipelined MFMA angle projection. Batch k's MFMA
    // stores go to slab[k&1]; batch k-1's flush (registers only) overlaps
    // them; one lgkm drain per batch.
    {
        int j = 0;
        const int aBeg = __builtin_amdgcn_readfirstlane(sA0[16 * w]);
        const int aEnd = __builtin_amdgcn_readfirstlane(sA0[16 * w + 15] + sAn[16 * w + 15]);
        int nextB = __builtin_amdgcn_readfirstlane(sA0[16 * w] + sAn[16 * w]);
        float aa0 = 0.0f, aa1 = 0.0f;
        const short8* WB = (const short8*)Wangpk;
        unsigned short* msg0 = sPh + (16 * w) * 136;
        unsigned short* msg1 = sMsg + (16 * w) * 136;
        unsigned int* m32_0 = sP32 + (16 * w) * 68;
        unsigned int* m32_1 = (unsigned int*)sMsg + (16 * w) * 68;

#define FLUSH_TO(AIDX)                                                           \
        while ((AIDX) >= nextB && j < 15) {                                      \
            At32[(16 * w + j) * 68 + l] = pk2(aa0, aa1);                         \
            aa0 = 0.0f; aa1 = 0.0f;                                              \
            ++j;                                                                 \
            nextB = __builtin_amdgcn_readfirstlane(sA0[16 * w + j] + sAn[16 * w + j]); \
        }

        // prologue: prefetch first batch's A-frag and gate gathers
        short8 afN = {0, 0, 0, 0, 0, 0, 0, 0};
        if (aBeg < aEnd && q < 2 && aBeg + c < aEnd)
            afN = *(const short8*)(angBS + (size_t)(aBeg + c) * 16 + q * 8);
        unsigned int gvvP[16], mvvP[16];
        if (aBeg < aEnd) {
#pragma unroll
            for (int r16 = 0; r16 < 16; ++r16) {
                const int aa = (aBeg + r16 < aEnd) ? aBeg + r16 : aEnd - 1;
                gvvP[r16] = Gq[(size_t)katS[aa] * 64 + l];
            }
        }

        int aPrev = -1;
        int phase = 0;
        for (int a0 = aBeg; a0 < aEnd; a0 += 16) {
            const short8 afA = afN;
            // prefetch next batch's A-frag (lands during this batch's work)
            short8 afZ = {0, 0, 0, 0, 0, 0, 0, 0};
            afN = afZ;
            if (q < 2 && a0 + 16 + c < aEnd)
                afN = *(const short8*)(angBS + (size_t)(a0 + 16 + c) * 16 + q * 8);

            // MFMA -> msg slab[phase] (stores go in flight)
            unsigned short* m = phase ? msg1 : msg0;
#pragma unroll
            for (int nt = 0; nt < 8; ++nt) {
                f32x4v d = mfma_bf16(afA, WB[nt * 64 + l], zz);
#pragma unroll
                for (int r = 0; r < 4; ++r)
                    m[(q * 4 + r) * 136 + nt * 16 + c] = f2bf(d[r]);
            }

            // flush previous batch (pure register VALU) while stores fly
            if (aPrev >= 0) {
#pragma unroll
                for (int r16 = 0; r16 < 16; ++r16) {
                    const int a = aPrev + r16;
                    FLUSH_TO(a)
                    aa0 = fmaf(blo(mvvP[r16]), blo(gvvP[r16]), aa0);
                    aa1 = fmaf(bhi(mvvP[r16]), bhi(gvvP[r16]), aa1);
                }
                // gate gathers for THIS batch (consumed next iteration)
#pragma unroll
                for (int r16 = 0; r16 < 16; ++r16) {
                    const int aa = (a0 + r16 < aEnd) ? a0 + r16 : aEnd - 1;
                    gvvP[r16] = Gq[(size_t)katS[aa] * 64 + l];
                }
            }

            // single drain: this batch's msg stores complete before the
            // cross-lane uint reads (type-punned RAW; R17 lesson). The other
            // slab's prior reads are already ordered by the previous drain.
            asm volatile("s_waitcnt lgkmcnt(0)" ::: "memory");
            __builtin_amdgcn_sched_barrier(0);

            unsigned int* m32 = phase ? m32_1 : m32_0;
#pragma unroll
            for (int r16 = 0; r16 < 16; ++r16) mvvP[r16] = m32[r16 * 68 + l];

            aPrev = a0;
            phase ^= 1;
        }
        // epilogue: flush the final batch
        if (aPrev >= 0) {
#pragma unroll
            for (int r16 = 0; r16 < 16; ++r16) {
                const int a = aPrev + r16;
                FLUSH_TO(a)
                aa0 = fmaf(blo(mvvP[r16]), blo(gvvP[r16]), aa0);
                aa1 = fmaf(bhi(mvvP[r16]), bhi(gvvP[r16]), aa1);
            }
        }
        At32[(16 * w + j) * 68 + l] = pk2(aa0, aa1);
        for (int jj = j + 1; jj < 16; ++jj) At32[(16 * w + jj) * 68 + l] = 0u;
#undef FLUSH_TO
    }
    // Fence A: At32 (uint) writes of Phase 0 must be LDS-complete and not
    // reorderable vs the short8 LOAD_AF reads below (type-punned RAW).
    // Placed BEFORE STAGE_SP so the Pe gathers stay in flight across GEMM1.
    asm volatile("s_waitcnt lgkmcnt(0)" ::: "memory");
    __builtin_amdgcn_sched_barrier(0);

    // stage Pe sums into the now-free sPh slab (consumed in GEMM2 epilogue;
    // gathers overlap GEMM1). Wave-private.
    STAGE_SP(Pe1q, Pe2q)

    const short8* Bp1 = (const short8*)Bpk3;
    const short8* Bp2 = Bp1 + 2048;
    const short8* Bp3 = Bp2 + 2048;
    const short8* W0e = (const short8*)We0pk;
    const short8* W0a = (const short8*)Wa0pk;

    short8 af[4];
#define LOAD_AF                                                                  \
    _Pragma("unroll") for (int kc = 0; kc < 4; ++kc)                             \
        af[kc] = *(const short8*)(At + (16 * w + c) * 136 + kc * 32 + q * 8);
// transpose from packed er2: row=edge (q*4+r), col=feature (nt*16+c)
#define TRANSPOSE_ER2                                                            \
    _Pragma("unroll") for (int nt = 0; nt < 8; ++nt) {                           \
        At[(16 * w + q * 4 + 0) * 136 + nt * 16 + c] = (unsigned short)er2[2 * nt];        \
        At[(16 * w + q * 4 + 1) * 136 + nt * 16 + c] = (unsigned short)(er2[2 * nt] >> 16);\
        At[(16 * w + q * 4 + 2) * 136 + nt * 16 + c] = (unsigned short)er2[2 * nt + 1];    \
        At[(16 * w + q * 4 + 3) * 136 + nt * 16 + c] = (unsigned short)(er2[2 * nt + 1] >> 16);\
    }

    unsigned int er2[16];

    // ---- GEMM1: agg @ Wtb; e += swish(. + btb)  (two nt-halves, acc[4])
    LOAD_AF
#pragma unroll 1
    for (int h = 0; h < 2; ++h) {
        // prefetch this half's e-old rows before the MFMAs (static indices)
        unsigned int eold[8];
#pragma unroll
        for (int s = 0; s < 8; ++s) eold[s] = epB[(h * 8 + s) * 64 + l];
        f32x4v acc[4];
#pragma unroll
        for (int n2 = 0; n2 < 4; ++n2) acc[n2] = zz;
#pragma unroll
        for (int n2 = 0; n2 < 4; ++n2)
#pragma unroll
            for (int kc = 0; kc < 4; ++kc)
                acc[n2] = mfma_bf16(af[kc], Bp1[(kc * 8 + h * 4 + n2) * 64 + l], acc[n2]);
#pragma unroll
        for (int n2 = 0; n2 < 4; ++n2) {
            const int nt = h * 4 + n2;
            const unsigned int e0 = eold[2 * n2];
            const unsigned int e1 = eold[2 * n2 + 1];
            const float bt = btb[nt * 16 + c];
            er2[2 * nt] = pk2(blo(e0) + swishf_(acc[n2][0] + bt),
                              bhi(e0) + swishf_(acc[n2][1] + bt));
            er2[2 * nt + 1] = pk2(blo(e1) + swishf_(acc[n2][2] + bt),
                                  bhi(e1) + swishf_(acc[n2][3] + bt));
        }
    }
    TRANSPOSE_ER2   // wave-private slab

    // Fence B: orders (a) TRANSPOSE_ER2's ushort At writes vs GEMM2's short8
    // LOAD_AF reads and (b) STAGE_SP(Pe)'s uint4 sPh writes vs GEMM2's ushort
    // sPh reads. Pe gathers are long done (a full GEMM elapsed).
    asm volatile("s_waitcnt lgkmcnt(0)" ::: "memory");
    __builtin_amdgcn_sched_barrier(0);

    // ---- GEMM2: e @ We1[256:384]; e += swish(. + be1 + Psum) * (ef0@We0)
    LOAD_AF
#pragma unroll 1
    for (int h = 0; h < 2; ++h) {
        f32x4v acc[4];
#pragma unroll
        for (int n2 = 0; n2 < 4; ++n2) acc[n2] = zz;
#pragma unroll
        for (int n2 = 0; n2 < 4; ++n2)
#pragma unroll
            for (int kc = 0; kc < 4; ++kc)
                acc[n2] = mfma_bf16(af[kc], Bp2[(kc * 8 + h * 4 + n2) * 64 + l], acc[n2]);
        // sc = ef0 @ We0 via MFMA; D(row=q*4+r, col=nt*16+c) matches use.
        f32x4v scv[4];
#pragma unroll
        for (int n2 = 0; n2 < 4; ++n2)
            scv[n2] = mfma_bf16(afE, W0e[(h * 4 + n2) * 64 + l], zz);
#pragma unroll
        for (int n2 = 0; n2 < 4; ++n2) {
            const int nt = h * 4 + n2;
            const int fo = nt * 16 + c;
            const float bt = be1[fo];
            float vv[4];
#pragma unroll
            for (int r = 0; r < 4; ++r) {
                const float p12 = bf2f(sPh[(16 * w + q * 4 + r) * 136 + fo]);
                const float x = acc[n2][r] + bt + p12;
                const unsigned int eold = er2[2 * nt + (r >> 1)];
                const float eb = (r & 1) ? bhi(eold) : blo(eold);
                vv[r] = eb + swishf_(x) * scv[n2][r];
            }
            er2[2 * nt] = pk2(vv[0], vv[1]);
            er2[2 * nt + 1] = pk2(vv[2], vv[3]);
            epB[(2 * nt) * 64 + l] = er2[2 * nt];          // coalesced
            epB[(2 * nt + 1) * 64 + l] = er2[2 * nt + 1];  // coalesced
        }
    }
    STAGE_SP(Pa1q, Pa2q)
    TRANSPOSE_ER2

    // ---- GEMM3: e @ Wa1[256:384]; m -> At (bf16) -> mPq at recv-sorted slots
    LOAD_AF
#pragma unroll 1
    for (int h = 0; h < 2; ++h) {
        f32x4v acc[4];
#pragma unroll
        for (int n2 = 0; n2 < 4; ++n2) acc[n2] = zz;
#pragma unroll
        for (int n2 = 0; n2 < 4; ++n2)
#pragma unroll
            for (int kc = 0; kc < 4; ++kc)
                acc[n2] = mfma_bf16(af[kc], Bp3[(kc * 8 + h * 4 + n2) * 64 + l], acc[n2]);
        f32x4v scv[4];
#pragma unroll
        for (int n2 = 0; n2 < 4; ++n2)
            scv[n2] = mfma_bf16(afE, W0a[(h * 4 + n2) * 64 + l], zz);
#pragma unroll
        for (int n2 = 0; n2 < 4; ++n2) {
            const int nt = h * 4 + n2;
            const int fo = nt * 16 + c;
            const float bt = ba1[fo];
#pragma unroll
            for (int r = 0; r < 4; ++r) {
                const float p12 = bf2f(sPh[(16 * w + q * 4 + r) * 136 + fo]);
                const float x = acc[n2][r] + bt + p12;
                At[(16 * w + q * 4 + r) * 136 + fo] = f2bf(swishf_(x) * scv[n2][r]);
            }
        }
    }
#pragma unroll
    for (int j = 0; j < 16; ++j) {
        const int ep = epos[wbase + j];
        mPq[(size_t)ep * 64 + l] = At32[(16 * w + j) * 68 + l];  // 256B full-line row
    }
#undef LOAD_AF
#undef TRANSPOSE_ER2
#undef STAGE_SP
}

// dv aggregation (streaming reads: mPq is recv-sorted) fused with v update + vq.
// 4-way unrolled with paired accumulators.
__global__ void k_dvagg(const unsigned int* __restrict__ mPq,
                        const int* __restrict__ startR, const int* __restrict__ cntR,
                        float* __restrict__ v, unsigned int* __restrict__ vq, int N) {
    const int a = blockIdx.x * 4 + (threadIdx.x >> 6);
    if (a >= N) return;
    const int l = threadIdx.x & 63;
    const int s0 = startR[a], n = cntR[a];
    float a0 = 0.0f, a1 = 0.0f, b0 = 0.0f, b1 = 0.0f;
    int i = 0;
    for (; i + 4 <= n; i += 4) {
        const unsigned int u0 = mPq[(size_t)(s0 + i + 0) * 64 + l];
        const unsigned int u1 = mPq[(size_t)(s0 + i + 1) * 64 + l];
        const unsigned int u2 = mPq[(size_t)(s0 + i + 2) * 64 + l];
        const unsigned int u3 = mPq[(size_t)(s0 + i + 3) * 64 + l];
        a0 += blo(u0) + blo(u1);
        a1 += bhi(u0) + bhi(u1);
        b0 += blo(u2) + blo(u3);
        b1 += bhi(u2) + bhi(u3);
    }
    for (; i < n; ++i) {
        const unsigned int u = mPq[(size_t)(s0 + i) * 64 + l];
        a0 += blo(u);
        a1 += bhi(u);
    }
    a0 += b0;
    a1 += b1;
    const float v0 = v[(size_t)a * 128 + 2 * l] + a0;
    const float v1 = v[(size_t)a * 128 + 2 * l + 1] + a1;
    v[(size_t)a * 128 + 2 * l] = v0;
    v[(size_t)a * 128 + 2 * l + 1] = v1;
    vq[(size_t)a * 64 + l] = pk2(v0, v1);
}

__global__ void k_readout(const float* __restrict__ v,
                          const float* __restrict__ W1, const float* __restrict__ b1,
                          const float* __restrict__ W2, const float* __restrict__ b2,
                          const float* __restrict__ W3, const float* __restrict__ b3,
                          float* __restrict__ out) {
    __shared__ float At[128 * 36];
    const int t = threadIdx.x;
    const int tn = t & 31, tm = t >> 5;
    const int f0 = tn << 2;
    const size_t base = (size_t)blockIdx.x * 32;
    {
        const int m = t & 31, cb = t >> 5;
        const float4* src = (const float4*)(v + (base + m) * 128);
#pragma unroll
        for (int i = 0; i < 4; ++i) {
            const int c = cb + (i << 3);
            const float4 ld = src[c];
            float* dst = At + (c << 2) * 32 + m;
            dst[0] = ld.x; dst[32] = ld.y; dst[64] = ld.z; dst[96] = ld.w;
        }
    }
    __syncthreads();
    float4 acc[4] = {};
    gemm32f<32>(At, W1, tm, f0, acc);
    {
        const float4 bv1 = *(const float4*)(b1 + f0);
#pragma unroll
        for (int j = 0; j < 4; ++j) acc[j] = f4swish(f4add(acc[j], bv1));
    }
    __syncthreads();
#pragma unroll
    for (int i = 0; i < 4; ++i) {
        float4 w0;
        w0.x = getc(acc[0], i); w0.y = getc(acc[1], i); w0.z = getc(acc[2], i); w0.w = getc(acc[3], i);
        *(float4*)(At + (f0 + i) * 36 + (tm << 2)) = w0;
    }
    __syncthreads();
    float4 acc2[4] = {};
    gemm32f<36>(At, W2, tm, f0, acc2);
    const float4 bv2 = *(const float4*)(b2 + f0);
    const float4 w3v = *(const float4*)(W3 + f0);
#pragma unroll
    for (int j = 0; j < 4; ++j) {
        const float4 h = f4swish(f4add(acc2[j], bv2));
        float p = h.x * w3v.x + h.y * w3v.y + h.z * w3v.z + h.w * w3v.w;
        p += __shfl_xor(p, 16);
        p += __shfl_xor(p, 8);
        p += __shfl_xor(p, 4);
        p += __shfl_xor(p, 2);
        p += __shfl_xor(p, 1);
        if (tn == 0) out[base + (tm << 2) + j] = p + b3[0];
    }
}

// ---------------------------------------------------------------------------
extern "C" void kernel_launch(void* const* d_in, const int* in_sizes, int n_in,
                              void* d_out, int out_size, void* d_ws, size_t ws_size,
                              hipStream_t stream) {
    const int N = in_sizes[0];
    const int E = in_sizes[2];
    const int A = in_sizes[4];
    const int NG = in_sizes[6];

    const int* an = (const int*)d_in[0];
    const int* ei = (const int*)d_in[1];
    const float* dist = (const float*)d_in[2];
    const int* tb = (const int*)d_in[3];
    const float* rnorm = (const float*)d_in[4];
    const float* cosang = (const float*)d_in[5];
    const int* tnb = (const int*)d_in[6];
    const int* tna = (const int*)d_in[7];
    const float* emb = (const float*)d_in[8];
    const float* Wenc = (const float*)d_in[9];
    const float* benc = (const float*)d_in[10];
    const float* Wang = (const float*)d_in[11];
    const float* Wg = (const float*)d_in[12];
    const float* bg = (const float*)d_in[13];
    const float* Wtb = (const float*)d_in[14];
    const float* btb = (const float*)d_in[15];
    const float* We1 = (const float*)d_in[16];
    const float* be1 = (const float*)d_in[17];
    const float* We0 = (const float*)d_in[18];
    const float* Wa1 = (const float*)d_in[19];
    const float* ba1 = (const float*)d_in[20];
    const float* Wa0 = (const float*)d_in[21];
    const float* W1 = (const float*)d_in[22];
    const float* b1 = (const float*)d_in[23];
    const float* W2 = (const float*)d_in[24];
    const float* b2 = (const float*)d_in[25];
    const float* W3 = (const float*)d_in[26];
    const float* b3 = (const float*)d_in[27];
    float* out = (float*)d_out;

    float* ws = (float*)d_ws;
    size_t off = 0;
    auto alloc = [&](size_t n) { float* p = ws + off; off += (n + 3) & ~(size_t)3; return p; };
    unsigned int* ePq = (unsigned int*)alloc((size_t)E * 64);   // e bf16, slot-major
    unsigned int* mPq = (unsigned int*)alloc((size_t)E * 64);   // m bf16, recv-sorted rows
    float* v_ = alloc((size_t)N * 128);
    unsigned int* vq = (unsigned int*)alloc((size_t)N * 64);    // v bf16-packed
    unsigned int* Gq = (unsigned int*)alloc((size_t)N * 64);    // gate bf16
    unsigned int* Pe1q = (unsigned int*)alloc((size_t)N * 64);
    unsigned int* Pe2q = (unsigned int*)alloc((size_t)N * 64);
    unsigned int* Pa1q = (unsigned int*)alloc((size_t)N * 64);
    unsigned int* Pa2q = (unsigned int*)alloc((size_t)N * 64);
    unsigned int* ef0q = (unsigned int*)alloc((size_t)E * 4);   // ef0 bf16x8 A-frag rows
    unsigned short* angB = (unsigned short*)alloc((size_t)A * 8);   // bf16 ang feats
    unsigned short* angBS = (unsigned short*)alloc((size_t)A * 8);  // bf16, ij-sorted
    int* kat = (int*)alloc((size_t)A);
    int* katS = (int*)alloc((size_t)A);
    int* iij = (int*)alloc((size_t)A);
    int* cnt = (int*)alloc((size_t)E);
    int* start = (int*)alloc((size_t)E);
    int* fill = (int*)alloc((size_t)E);
    int* cntR = (int*)alloc((size_t)N);
    int* startR = (int*)alloc((size_t)N);
    int* fillR = (int*)alloc((size_t)N);
    int* epos = (int*)alloc((size_t)E);
    int* bsum = (int*)alloc(512);
    int* boff = (int*)alloc(256);
    int* acum = boff + 128;
    unsigned short* Bpk = (unsigned short*)alloc((size_t)32 * 8192);  // 32 mats bf16
    unsigned short* Spk = (unsigned short*)alloc((size_t)12 * 2048);  // Wang/We0/Wa0 B-frags

    const int nscanE = (E + 2047) / 2048;
    const int nscanR = (N + 2047) / 2048;

    (void)hipMemsetAsync(cnt, 0, (size_t)E * 4, stream);
    (void)hipMemsetAsync(fill, 0, (size_t)E * 4, stream);
    (void)hipMemsetAsync(cntR, 0, (size_t)N * 4, stream);
    (void)hipMemsetAsync(fillR, 0, (size_t)N * 4, stream);
    k_offsets<<<1, 64, 0, stream>>>(tnb, tna, NG, boff, acum);
    k_angle_setup<<<(A + 255) / 256, 256, 0, stream>>>(tb, rnorm, cosang, ei, E, A, NG,
                                                       boff, acum, angB, kat, iij, cnt);
    // k_edge_init also produces cntR (recv histogram) -> before the N-scan
    k_edge_init<<<E / 16, 512, 0, stream>>>(dist, Wenc, benc, ei, E, cntR, ePq, ef0q);
    k_scan1<<<nscanE, 256, 0, stream>>>(cnt, start, bsum, E);
    k_scan2<<<1, 256, 0, stream>>>(bsum, nscanE);
    k_scan3<<<(E + 255) / 256, 256, 0, stream>>>(start, bsum, E);
    k_scatter<<<(A + 255) / 256, 256, 0, stream>>>(angB, kat, iij, start, fill, angBS, katS, A);
    k_scan1<<<nscanR, 256, 0, stream>>>(cntR, startR, bsum, N);
    k_scan2<<<1, 256, 0, stream>>>(bsum, nscanR);
    k_scan3<<<(N + 255) / 256, 256, 0, stream>>>(startR, bsum, N);
    k_scatter_recv<<<(E + 255) / 256, 256, 0, stream>>>(ei, E, startR, fillR, epos);
    k_pack<<<256, 256, 0, stream>>>(Wg, Wtb, We1, Wa1, Bpk);
    k_pack_s<<<96, 64, 0, stream>>>(Wang, We0, Wa0, Spk);
    k_atom_init<<<(int)(((size_t)N * 64 + 255) / 256), 256, 0, stream>>>(an, emb, v_, vq, N);

    for (int b = 0; b < 4; ++b) {
        k_atom_pre<<<dim3(N / 64, 5), 256, 0, stream>>>(
            vq, Bpk + (size_t)(b * 8) * 16384, bg + b * 128,
            Gq, Pe1q, Pe2q, Pa1q, Pa2q);
        k_edge<<<E / 32, 128, 0, stream>>>(
            angBS, katS, start, cnt, Gq, Spk + (size_t)b * 4096, ef0q,
            ePq, ei, E, Pe1q, Pe2q, Pa1q, Pa2q, epos,
            Bpk + (size_t)(b * 8 + 5) * 16384,
            btb + b * 128, be1 + b * 128,
            Spk + (size_t)(4 + b) * 4096, ba1 + b * 128,
            Spk + (size_t)(8 + b) * 4096, mPq);
        k_dvagg<<<(N + 3) / 4, 256, 0, stream>>>(mPq, startR, cntR, v_, vq, N);
    }
    k_readout<<<N / 32, 256, 0, stream>>>(v_, W1, b1, W2, b2, W3, b3, out);
}

// Round 14
// 954.739 us; speedup vs baseline: 1.4429x; 1.4429x over previous
//
#include <hip/hip_runtime.h>

// ---------------------------------------------------------------------------
// M3GNet forward. N=8000, E=200000, A=400000, NG=100, FD=128.
// R30 = R28 restored (963.5us best). R29's Phase-0 double-buffer pipeline
// forced gvv/mvv (32 VGPRs) loop-carried -> VGPR 60->88, residency 36->20%,
// k_edge 163->269us + a 30ms skew-tail outlier. Third confirmation of the
// session rule: extending vector-payload live ranges across iterations/fences
// loses more residency than the ILP gains (R23 spill, R29 regalloc).
// R28 config: 128thr/2wave/32edge blocks, LDS 17920; R27 sc-via-MFMA; R22
// fence discipline; R21 prefetches; R24 hist fold.
// ---------------------------------------------------------------------------

typedef short short8 __attribute__((ext_vector_type(8)));
typedef float f32x4v __attribute__((ext_vector_type(4)));
typedef __bf16 bf16x2_t __attribute__((ext_vector_type(2)));

__device__ __forceinline__ float sigmoidf_(float x) { return 1.0f / (1.0f + __expf(-x)); }
__device__ __forceinline__ float swishf_(float x) { return x * sigmoidf_(x); }

// packed bf16 convert: dst.lo = bf16(a), dst.hi = bf16(b). RNE.
__device__ __forceinline__ unsigned int pk2(float a, float b) {
    bf16x2_t v = {(__bf16)a, (__bf16)b};
    return __builtin_bit_cast(unsigned int, v);
}
__device__ __forceinline__ unsigned short f2bf(float x) {
    return __builtin_bit_cast(unsigned short, (__bf16)x);
}
__device__ __forceinline__ float bf2f(unsigned short u) {
    return __uint_as_float(((unsigned int)u) << 16);
}
__device__ __forceinline__ float blo(unsigned int u) { return __uint_as_float(u << 16); }
__device__ __forceinline__ float bhi(unsigned int u) { return __uint_as_float(u & 0xffff0000u); }
__device__ __forceinline__ unsigned int addbf2(unsigned int a, unsigned int b) {
    return pk2(blo(a) + blo(b), bhi(a) + bhi(b));
}

__device__ __forceinline__ f32x4v mfma_bf16(short8 a, short8 b, f32x4v c) {
    return __builtin_amdgcn_mfma_f32_16x16x32_bf16(a, b, c, 0, 0, 0);
}

__device__ __forceinline__ float4 f4add(float4 a, float4 b) {
    return make_float4(a.x + b.x, a.y + b.y, a.z + b.z, a.w + b.w);
}
__device__ __forceinline__ float4 f4swish(float4 a) {
    return make_float4(swishf_(a.x), swishf_(a.y), swishf_(a.z), swishf_(a.w));
}
__device__ __forceinline__ float getc(const float4& v, int i) {
    return i == 0 ? v.x : (i == 1 ? v.y : (i == 2 ? v.z : v.w));
}

#define FMA4(J, A) \
    acc[J].x = fmaf(A, bv.x, acc[J].x); acc[J].y = fmaf(A, bv.y, acc[J].y); \
    acc[J].z = fmaf(A, bv.z, acc[J].z); acc[J].w = fmaf(A, bv.w, acc[J].w)

template <int S>
__device__ __forceinline__ void gemm32f(const float* As, const float* __restrict__ B,
                                        int tm, int f0, float4 acc[4]) {
#pragma unroll 4
    for (int k = 0; k < 128; ++k) {
        const float4 a0 = *(const float4*)(As + k * S + (tm << 2));
        const float4 bv = *(const float4*)(B + (k << 7) + f0);
        FMA4(0, a0.x); FMA4(1, a0.y); FMA4(2, a0.z); FMA4(3, a0.w);
    }
}

// ---------------------------------------------------------------------------
__global__ void k_offsets(const int* __restrict__ tnb, const int* __restrict__ tna,
                          int NG, int* __restrict__ boff, int* __restrict__ acum) {
    if (threadIdx.x == 0 && blockIdx.x == 0) {
        int ab = 0, aa = 0;
        for (int g = 0; g < NG; ++g) {
            boff[g] = ab;
            ab += tnb[g];
            aa += tna[g];
            acum[g] = aa;
        }
    }
}

__global__ void k_angle_setup(const int* __restrict__ tb, const float* __restrict__ rnorm,
                              const float* __restrict__ cosang, const int* __restrict__ ei,
                              int E, int A, int NG,
                              const int* __restrict__ boff, const int* __restrict__ acum,
                              unsigned short* __restrict__ ang,
                              int* __restrict__ kat, int* __restrict__ iij,
                              int* __restrict__ cnt) {
    const int a = blockIdx.x * 256 + threadIdx.x;
    if (a >= A) return;
    int lo = 0, hi = NG - 1;
    while (lo < hi) {
        const int mid = (lo + hi) >> 1;
        if (a < acum[mid]) hi = mid; else lo = mid + 1;
    }
    const int off = boff[lo];
    iij[a] = tb[2 * a] + off;
    kat[a] = ei[(size_t)E + tb[2 * a + 1] + off];
    atomicAdd(&cnt[tb[2 * a] + off], 1);

    const float r = rnorm[a], c = cosang[a];
    const float rinv = 1.0f / r;
    const float x = r * 0.25f;
    const float fc = 1.0f + x * x * x * (-10.0f + x * (15.0f - 6.0f * x));
    const float fc2 = fc * fc;
    const float p2 = 1.5f * c * c - 0.5f;
    const float p3 = 2.5f * c * c * c - 1.5f * c;
    union { unsigned int ui[8]; uint4 v[2]; } pkk;
#pragma unroll
    for (int n = 0; n < 4; ++n) {
        const float rad = __sinf(r * (float)(n + 1) * 0.7853981633974483f) * rinv * fc2;
        pkk.ui[n * 2 + 0] = pk2(rad, rad * c);
        pkk.ui[n * 2 + 1] = pk2(rad * p2, rad * p3);
    }
    uint4* ap = (uint4*)(ang + (size_t)a * 16);
    ap[0] = pkk.v[0];
    ap[1] = pkk.v[1];
}

__global__ void k_scan1(const int* __restrict__ cnt, int* __restrict__ start,
                        int* __restrict__ bsum, int n) {
    __shared__ int sh[256];
    const int t = threadIdx.x;
    const int base = blockIdx.x * 2048 + t * 8;
    int v[8], s = 0;
#pragma unroll
    for (int i = 0; i < 8; ++i) { v[i] = (base + i < n) ? cnt[base + i] : 0; s += v[i]; }
    sh[t] = s;
    __syncthreads();
    for (int off = 1; off < 256; off <<= 1) {
        int x = (t >= off) ? sh[t - off] : 0;
        __syncthreads();
        sh[t] += x;
        __syncthreads();
    }
    if (t == 255) bsum[blockIdx.x] = sh[255];
    int run = sh[t] - s;
#pragma unroll
    for (int i = 0; i < 8; ++i) { if (base + i < n) start[base + i] = run; run += v[i]; }
}

__global__ void k_scan2(int* __restrict__ bsum, int nb) {
    __shared__ int sh[256];
    const int t = threadIdx.x;
    int v = (t < nb) ? bsum[t] : 0;
    sh[t] = v;
    __syncthreads();
    for (int off = 1; off < 256; off <<= 1) {
        int x = (t >= off) ? sh[t - off] : 0;
        __syncthreads();
        sh[t] += x;
        __syncthreads();
    }
    if (t < nb) bsum[t] = sh[t] - v;
}

__global__ void k_scan3(int* __restrict__ start, const int* __restrict__ bsum, int n) {
    const int i = blockIdx.x * 256 + threadIdx.x;
    if (i < n) start[i] += bsum[i >> 11];
}

__global__ void k_scatter(const unsigned short* __restrict__ ang,
                          const int* __restrict__ kat, const int* __restrict__ iij,
                          const int* __restrict__ start, int* __restrict__ fill,
                          unsigned short* __restrict__ angS, int* __restrict__ katS, int A) {
    const int a = blockIdx.x * 256 + threadIdx.x;
    if (a >= A) return;
    const int ij = iij[a];
    const int pos = start[ij] + atomicAdd(&fill[ij], 1);
    const uint4* src = (const uint4*)(ang + (size_t)a * 16);
    uint4* dst = (uint4*)(angS + (size_t)pos * 16);
    dst[0] = src[0];
    dst[1] = src[1];
    katS[pos] = kat[a];
}

__global__ void k_scatter_recv(const int* __restrict__ ei, int E,
                               const int* __restrict__ startR, int* __restrict__ fillR,
                               int* __restrict__ epos) {
    const int e = blockIdx.x * 256 + threadIdx.x;
    if (e < E) {
        const int r = ei[(size_t)E + e];
        epos[e] = startR[r] + atomicAdd(&fillR[r], 1);
    }
}

// pack 32 weight matrices into MFMA B-frag layout (bf16).
// mat = b*8 + {0:Wg, 1:We1a, 2:We1b, 3:Wa1a, 4:Wa1b, 5:Wtb, 6:We1c, 7:Wa1c}
__global__ void k_pack(const float* __restrict__ Wg, const float* __restrict__ Wtb,
                       const float* __restrict__ We1, const float* __restrict__ Wa1,
                       unsigned short* __restrict__ Bpk) {
    const int gid = blockIdx.x * 256 + threadIdx.x;  // 0..65535
    const int mat = gid >> 11;
    const int t2 = gid & 2047;
    const int b = mat >> 3, which = mat & 7;
    const float* W;
    switch (which) {
        case 0: W = Wg + (size_t)b * 16384; break;
        case 1: W = We1 + (size_t)b * 49152; break;
        case 2: W = We1 + (size_t)b * 49152 + 16384; break;
        case 3: W = Wa1 + (size_t)b * 49152; break;
        case 4: W = Wa1 + (size_t)b * 49152 + 16384; break;
        case 5: W = Wtb + (size_t)b * 16384; break;
        case 6: W = We1 + (size_t)b * 49152 + 32768; break;
        default: W = Wa1 + (size_t)b * 49152 + 32768; break;
    }
    const int kc = t2 >> 9, nt = (t2 >> 6) & 7, lane = t2 & 63;
    const int q = lane >> 4, cc = lane & 15;
    const int col = nt * 16 + cc;
    union { unsigned short us[8]; uint4 v; } pk;
#pragma unroll
    for (int j = 0; j < 8; ++j)
        pk.us[j] = f2bf(W[(size_t)(kc * 32 + q * 8 + j) * 128 + col]);
    *(uint4*)(Bpk + (size_t)mat * 16384 + (size_t)((kc * 8 + nt) * 64 + lane) * 8) = pk.v;
}

// pack small-K matrices into MFMA B-frag layout (K padded to 32 with 0).
// m = type*4 + b; type 0: Wang (K=16), type 1: We0 (K=5), type 2: Wa0 (K=5).
__global__ void k_pack_s(const float* __restrict__ Wang, const float* __restrict__ We0g,
                         const float* __restrict__ Wa0g, unsigned short* __restrict__ Spk) {
    const int gid = blockIdx.x * 64 + threadIdx.x;  // 12 mats * 512 lanes
    const int m = gid >> 9;
    const int nt = (gid >> 6) & 7, lane = gid & 63;
    const int b = m & 3, type = m >> 2;
    const int q = lane >> 4, cc = lane & 15;
    const int col = nt * 16 + cc;
    const float* W;
    int K;
    if (type == 0)      { W = Wang + (size_t)b * 2048; K = 16; }
    else if (type == 1) { W = We0g + (size_t)b * 640;  K = 5;  }
    else                { W = Wa0g + (size_t)b * 640;  K = 5;  }
    union { unsigned short us[8]; uint4 v; } pk;
#pragma unroll
    for (int j = 0; j < 8; ++j) {
        const int k = q * 8 + j;
        pk.us[j] = (k < K) ? f2bf(W[(size_t)k * 128 + col]) : (unsigned short)0;
    }
    *(uint4*)(Spk + (size_t)m * 4096 + (size_t)(nt * 64 + lane) * 8) = pk.v;
}

// e init, slot-major layout: ePq[(strip*16 + s)*64 + lane], s = nt*2 + half.
// Also folds the recv-degree histogram and writes ef0q (A-frag-ready bf16x8:
// 5 rbf values + 3 zeros per edge).
__global__ void k_edge_init(const float* __restrict__ dist, const float* __restrict__ Wenc,
                            const float* __restrict__ benc,
                            const int* __restrict__ ei, int E, int* __restrict__ cntR,
                            unsigned int* __restrict__ ePq,
                            unsigned int* __restrict__ ef0q) {
    __shared__ float sarr[16][5];
    const int s = blockIdx.x, t = threadIdx.x;
    if (t < 16) {
        const float r = dist[s * 16 + t];
        const float rinv = 1.0f / r;
        float vv[5];
#pragma unroll
        for (int n = 0; n < 5; ++n) {
            vv[n] = 0.6324555320336759f * __sinf(r * (float)(n + 1) * 0.6283185307179586f) * rinv;
            sarr[t][n] = vv[n];
        }
        uint4 pq;
        pq.x = pk2(vv[0], vv[1]);
        pq.y = pk2(vv[2], vv[3]);
        pq.z = pk2(vv[4], 0.0f);
        pq.w = 0u;
        *(uint4*)(ef0q + (size_t)(s * 16 + t) * 4) = pq;
        atomicAdd(&cntR[ei[(size_t)E + s * 16 + t]], 1);
    }
    __syncthreads();
    const int lane = t >> 3, nt = t & 7;
    const int q = lane >> 4;
    const int f = nt * 16 + (lane & 15);
    float wv[5];
#pragma unroll
    for (int n = 0; n < 5; ++n) wv[n] = Wenc[n * 128 + f];
    const float bz = benc[f];
    float o[4];
#pragma unroll
    for (int r = 0; r < 4; ++r) {
        const int m = q * 4 + r;
        float acc = bz;
#pragma unroll
        for (int n = 0; n < 5; ++n) acc = fmaf(sarr[m][n], wv[n], acc);
        o[r] = swishf_(acc);
    }
    unsigned int* epB = ePq + (size_t)s * 1024;
    epB[(nt * 2) * 64 + lane] = pk2(o[0], o[1]);
    epB[(nt * 2 + 1) * 64 + lane] = pk2(o[2], o[3]);
}

// atom init: v fp32 + vq bf16-packed (lane j holds features 2j,2j+1)
__global__ void k_atom_init(const int* __restrict__ an, const float* __restrict__ emb,
                            float* __restrict__ v, unsigned int* __restrict__ vq, int N) {
    const size_t gid = (size_t)blockIdx.x * 256 + threadIdx.x;
    if (gid >= (size_t)N * 64) return;
    const int a = (int)(gid >> 6), j = (int)(gid & 63);
    const float2 e = *(const float2*)(emb + (size_t)an[a] * 128 + 2 * j);
    *(float2*)(v + (size_t)a * 128 + 2 * j) = e;
    vq[gid] = pk2(e.x, e.y);
}

// ---------------------------------------------------------------------------
// MFMA per-atom GEMMs: 64 atoms/block, wave w owns atoms 16w..16w+15.
// blockIdx.y = g selects the matrix (625 blocks/dispatch keeps all CUs busy).
__global__ void __launch_bounds__(256, 4) k_atom_pre(
    const unsigned int* __restrict__ vq,
    const unsigned short* __restrict__ Bpk5, const float* __restrict__ bg,
    unsigned int* __restrict__ Gq, unsigned int* __restrict__ Pe1q,
    unsigned int* __restrict__ Pe2q,
    unsigned int* __restrict__ Pa1q, unsigned int* __restrict__ Pa2q) {
    __shared__ __align__(16) unsigned short At[64 * 136];
    unsigned int* At32 = (unsigned int*)At;
    const int t = threadIdx.x;
    const int w = t >> 6, l = t & 63;
    const int q = l >> 4, c = l & 15;
    const int g = blockIdx.y;
    const int abase = blockIdx.x * 64 + 16 * w;

    const unsigned short* vh = (const unsigned short*)vq;
    short8 af[4];
#pragma unroll
    for (int kc = 0; kc < 4; ++kc)
        af[kc] = *(const short8*)(vh + (size_t)(abase + c) * 128 + kc * 32 + q * 8);

    const short8* Bp = (const short8*)(Bpk5 + (size_t)g * 16384);
    const f32x4v zz = {0.0f, 0.0f, 0.0f, 0.0f};
    f32x4v acc[8];
#pragma unroll
    for (int nt = 0; nt < 8; ++nt) acc[nt] = zz;
#pragma unroll
    for (int nt = 0; nt < 8; ++nt)
#pragma unroll
        for (int kc = 0; kc < 4; ++kc)
            acc[nt] = mfma_bf16(af[kc], Bp[(kc * 8 + nt) * 64 + l], acc[nt]);

    unsigned int* OUT = (g == 0) ? Gq : (g == 1) ? Pe1q : (g == 2) ? Pe2q
                      : (g == 3) ? Pa1q : Pa2q;
#pragma unroll
    for (int nt = 0; nt < 8; ++nt) {
        const int fo = nt * 16 + c;
        if (g == 0) {
            const float bz = bg[fo];
#pragma unroll
            for (int r = 0; r < 4; ++r)
                At[(16 * w + q * 4 + r) * 136 + fo] = f2bf(sigmoidf_(acc[nt][r] + bz));
        } else {
#pragma unroll
            for (int r = 0; r < 4; ++r)
                At[(16 * w + q * 4 + r) * 136 + fo] = f2bf(acc[nt][r]);
        }
    }
#pragma unroll
    for (int j = 0; j < 16; ++j)
        OUT[(size_t)(abase + j) * 64 + l] = At32[(16 * w + j) * 68 + l];
}

// ---------------------------------------------------------------------------
// Fused per-edge kernel: Phase 0 (MFMA angle batches) + 3 MFMA GEMMs, each
// GEMM computed in two nt-halves (acc[4]) to cut the register peak.
// 128 threads / 2 waves / 32 edges per block. All LDS state is wave-private
// -> NO cross-wave barrier. Type-punned LDS RAW seams ordered by lgkmcnt(0)+
// sched_barrier fences (R17 lesson). sc factors via MFMA (R27).
__global__ void __launch_bounds__(128, 4) k_edge(
    const unsigned short* __restrict__ angBS, const int* __restrict__ katS,
    const int* __restrict__ startA, const int* __restrict__ cntA,
    const unsigned int* __restrict__ Gq, const unsigned short* __restrict__ Wangpk,
    const unsigned int* __restrict__ ef0q,
    unsigned int* __restrict__ ePq, const int* __restrict__ ei, int E,
    const unsigned int* __restrict__ Pe1q, const unsigned int* __restrict__ Pe2q,
    const unsigned int* __restrict__ Pa1q, const unsigned int* __restrict__ Pa2q,
    const int* __restrict__ epos,
    const unsigned short* __restrict__ Bpk3,
    const float* __restrict__ btb, const float* __restrict__ be1,
    const unsigned short* __restrict__ We0pk, const float* __restrict__ ba1,
    const unsigned short* __restrict__ Wa0pk, unsigned int* __restrict__ mPq) {
    __shared__ __align__(16) unsigned short At[32 * 136];
    __shared__ __align__(16) unsigned short sPh[32 * 136];
    __shared__ int sA0[32], sAn[32];
    unsigned int* At32 = (unsigned int*)At;
    unsigned int* sP32 = (unsigned int*)sPh;

    const int t = threadIdx.x;
    const int w = t >> 6, l = t & 63;
    const int q = l >> 4, c = l & 15;
    const int g4 = l >> 4, l16 = l & 15;
    const size_t base = (size_t)blockIdx.x * 32;
    const int wbase = (int)base + 16 * w;
    const f32x4v zz = {0.0f, 0.0f, 0.0f, 0.0f};

    if (l < 16) {
        sA0[16 * w + l] = startA[wbase + l];
        sAn[16 * w + l] = cntA[wbase + l];
    }

    // prefetch this lane's edge-index rows (feeds STAGE_SP gather addresses)
    int eiS[4], eiR[4];
#pragma unroll
    for (int i = 0; i < 4; ++i) {
        eiS[i] = ei[wbase + i * 4 + g4];
        eiR[i] = ei[(size_t)E + wbase + i * 4 + g4];
    }

    // A-frag of ef0 (row = edge wbase+c, K=5 padded): q==0 lanes hold the 5
    // bf16 rbf values (+3 zeros); q>=1 lanes are zero.
    short8 afE = {0, 0, 0, 0, 0, 0, 0, 0};
    if (q == 0)
        afE = *(const short8*)((const unsigned short*)ef0q + (size_t)(wbase + c) * 8);

#define STAGE_SP(P1, P2)                                                         \
    _Pragma("unroll") for (int i = 0; i < 4; ++i) {                              \
        const int j = i * 4 + g4;                                                \
        const uint4 u1 = *(const uint4*)((P1) + (size_t)eiS[i] * 64 + l16 * 4);  \
        const uint4 u2 = *(const uint4*)((P2) + (size_t)eiR[i] * 64 + l16 * 4);  \
        uint4 o;                                                                 \
        o.x = addbf2(u1.x, u2.x); o.y = addbf2(u1.y, u2.y);                      \
        o.z = addbf2(u1.z, u2.z); o.w = addbf2(u1.w, u2.w);                      \
        *(uint4*)(sP32 + (16 * w + j) * 68 + l16 * 4) = o;                       \
    }

    unsigned int* epB = ePq + (size_t)(blockIdx.x * 2 + w) * 1024;  // slot-major

    // ---- Phase 0: MFMA angle projection, 16-angle batches through sPh slab.
    {
        int j = 0;
        const int aBeg = __builtin_amdgcn_readfirstlane(sA0[16 * w]);
        const int aEnd = __builtin_amdgcn_readfirstlane(sA0[16 * w + 15] + sAn[16 * w + 15]);
        int nextB = __builtin_amdgcn_readfirstlane(sA0[16 * w] + sAn[16 * w]);
        float aa0 = 0.0f, aa1 = 0.0f;
        const short8* WB = (const short8*)Wangpk;
        unsigned short* msg = sPh + (16 * w) * 136;
        unsigned int* msg32 = sP32 + (16 * w) * 68;

#define FLUSH_TO(AIDX)                                                           \
        while ((AIDX) >= nextB && j < 15) {                                      \
            At32[(16 * w + j) * 68 + l] = pk2(aa0, aa1);                         \
            aa0 = 0.0f; aa1 = 0.0f;                                              \
            ++j;                                                                 \
            nextB = __builtin_amdgcn_readfirstlane(sA0[16 * w + j] + sAn[16 * w + j]); \
        }

        // prologue: prefetch first batch's A-frag
        short8 afN = {0, 0, 0, 0, 0, 0, 0, 0};
        if (aBeg < aEnd && q < 2 && aBeg + c < aEnd)
            afN = *(const short8*)(angBS + (size_t)(aBeg + c) * 16 + q * 8);

        for (int a0 = aBeg; a0 < aEnd; a0 += 16) {
            const short8 afA = afN;
            // prefetch next batch's A-frag (lands during this batch's work)
            short8 afZ = {0, 0, 0, 0, 0, 0, 0, 0};
            afN = afZ;
            if (q < 2 && a0 + 16 + c < aEnd)
                afN = *(const short8*)(angBS + (size_t)(a0 + 16 + c) * 16 + q * 8);

            // uniform clamped kat loads + all 16 gate gathers, issued before
            // the MFMA/fence region (independent; land by flush time).
            unsigned int gvv[16];
#pragma unroll
            for (int r16 = 0; r16 < 16; ++r16) {
                const int aa = (a0 + r16 < aEnd) ? a0 + r16 : aEnd - 1;
                gvv[r16] = Gq[(size_t)katS[aa] * 64 + l];
            }

#pragma unroll
            for (int nt = 0; nt < 8; ++nt) {
                f32x4v d = mfma_bf16(afA, WB[nt * 64 + l], zz);
#pragma unroll
                for (int r = 0; r < 4; ++r)
                    msg[(q * 4 + r) * 136 + nt * 16 + c] = f2bf(d[r]);
            }
            // Fence 1: all lanes' msg stores complete before cross-lane reads.
            asm volatile("s_waitcnt lgkmcnt(0)" ::: "memory");
            __builtin_amdgcn_sched_barrier(0);

            unsigned int mvv[16];
#pragma unroll
            for (int r16 = 0; r16 < 16; ++r16) mvv[r16] = msg32[r16 * 68 + l];
            // Fence 2: reads drained before next batch's stores overwrite msg.
            asm volatile("s_waitcnt lgkmcnt(0)" ::: "memory");
            __builtin_amdgcn_sched_barrier(0);

#pragma unroll
            for (int r16 = 0; r16 < 16; ++r16) {
                const int a = a0 + r16;
                FLUSH_TO(a)
                aa0 = fmaf(blo(mvv[r16]), blo(gvv[r16]), aa0);
                aa1 = fmaf(bhi(mvv[r16]), bhi(gvv[r16]), aa1);
            }
        }
        At32[(16 * w + j) * 68 + l] = pk2(aa0, aa1);
        for (int jj = j + 1; jj < 16; ++jj) At32[(16 * w + jj) * 68 + l] = 0u;
#undef FLUSH_TO
    }
    // Fence A: At32 (uint) writes of Phase 0 must be LDS-complete and not
    // reorderable vs the short8 LOAD_AF reads below (type-punned RAW).
    // Placed BEFORE STAGE_SP so the Pe gathers stay in flight across GEMM1.
    asm volatile("s_waitcnt lgkmcnt(0)" ::: "memory");
    __builtin_amdgcn_sched_barrier(0);

    // stage Pe sums into the now-free sPh slab (consumed in GEMM2 epilogue;
    // gathers overlap GEMM1). Wave-private.
    STAGE_SP(Pe1q, Pe2q)

    const short8* Bp1 = (const short8*)Bpk3;
    const short8* Bp2 = Bp1 + 2048;
    const short8* Bp3 = Bp2 + 2048;
    const short8* W0e = (const short8*)We0pk;
    const short8* W0a = (const short8*)Wa0pk;

    short8 af[4];
#define LOAD_AF                                                                  \
    _Pragma("unroll") for (int kc = 0; kc < 4; ++kc)                             \
        af[kc] = *(const short8*)(At + (16 * w + c) * 136 + kc * 32 + q * 8);
// transpose from packed er2: row=edge (q*4+r), col=feature (nt*16+c)
#define TRANSPOSE_ER2                                                            \
    _Pragma("unroll") for (int nt = 0; nt < 8; ++nt) {                           \
        At[(16 * w + q * 4 + 0) * 136 + nt * 16 + c] = (unsigned short)er2[2 * nt];        \
        At[(16 * w + q * 4 + 1) * 136 + nt * 16 + c] = (unsigned short)(er2[2 * nt] >> 16);\
        At[(16 * w + q * 4 + 2) * 136 + nt * 16 + c] = (unsigned short)er2[2 * nt + 1];    \
        At[(16 * w + q * 4 + 3) * 136 + nt * 16 + c] = (unsigned short)(er2[2 * nt + 1] >> 16);\
    }

    unsigned int er2[16];

    // ---- GEMM1: agg @ Wtb; e += swish(. + btb)  (two nt-halves, acc[4])
    LOAD_AF
#pragma unroll 1
    for (int h = 0; h < 2; ++h) {
        // prefetch this half's e-old rows before the MFMAs (static indices)
        unsigned int eold[8];
#pragma unroll
        for (int s = 0; s < 8; ++s) eold[s] = epB[(h * 8 + s) * 64 + l];
        f32x4v acc[4];
#pragma unroll
        for (int n2 = 0; n2 < 4; ++n2) acc[n2] = zz;
#pragma unroll
        for (int n2 = 0; n2 < 4; ++n2)
#pragma unroll
            for (int kc = 0; kc < 4; ++kc)
                acc[n2] = mfma_bf16(af[kc], Bp1[(kc * 8 + h * 4 + n2) * 64 + l], acc[n2]);
#pragma unroll
        for (int n2 = 0; n2 < 4; ++n2) {
            const int nt = h * 4 + n2;
            const unsigned int e0 = eold[2 * n2];
            const unsigned int e1 = eold[2 * n2 + 1];
            const float bt = btb[nt * 16 + c];
            er2[2 * nt] = pk2(blo(e0) + swishf_(acc[n2][0] + bt),
                              bhi(e0) + swishf_(acc[n2][1] + bt));
            er2[2 * nt + 1] = pk2(blo(e1) + swishf_(acc[n2][2] + bt),
                                  bhi(e1) + swishf_(acc[n2][3] + bt));
        }
    }
    TRANSPOSE_ER2   // wave-private slab

    // Fence B: orders (a) TRANSPOSE_ER2's ushort At writes vs GEMM2's short8
    // LOAD_AF reads and (b) STAGE_SP(Pe)'s uint4 sPh writes vs GEMM2's ushort
    // sPh reads. Pe gathers are long done (a full GEMM elapsed).
    asm volatile("s_waitcnt lgkmcnt(0)" ::: "memory");
    __builtin_amdgcn_sched_barrier(0);

    // ---- GEMM2: e @ We1[256:384]; e += swish(. + be1 + Psum) * (ef0@We0)
    LOAD_AF
#pragma unroll 1
    for (int h = 0; h < 2; ++h) {
        f32x4v acc[4];
#pragma unroll
        for (int n2 = 0; n2 < 4; ++n2) acc[n2] = zz;
#pragma unroll
        for (int n2 = 0; n2 < 4; ++n2)
#pragma unroll
            for (int kc = 0; kc < 4; ++kc)
                acc[n2] = mfma_bf16(af[kc], Bp2[(kc * 8 + h * 4 + n2) * 64 + l], acc[n2]);
        // sc = ef0 @ We0 via MFMA; D(row=q*4+r, col=nt*16+c) matches use.
        f32x4v scv[4];
#pragma unroll
        for (int n2 = 0; n2 < 4; ++n2)
            scv[n2] = mfma_bf16(afE, W0e[(h * 4 + n2) * 64 + l], zz);
#pragma unroll
        for (int n2 = 0; n2 < 4; ++n2) {
            const int nt = h * 4 + n2;
            const int fo = nt * 16 + c;
            const float bt = be1[fo];
            float vv[4];
#pragma unroll
            for (int r = 0; r < 4; ++r) {
                const float p12 = bf2f(sPh[(16 * w + q * 4 + r) * 136 + fo]);
                const float x = acc[n2][r] + bt + p12;
                const unsigned int eold = er2[2 * nt + (r >> 1)];
                const float eb = (r & 1) ? bhi(eold) : blo(eold);
                vv[r] = eb + swishf_(x) * scv[n2][r];
            }
            er2[2 * nt] = pk2(vv[0], vv[1]);
            er2[2 * nt + 1] = pk2(vv[2], vv[3]);
            epB[(2 * nt) * 64 + l] = er2[2 * nt];          // coalesced
            epB[(2 * nt + 1) * 64 + l] = er2[2 * nt + 1];  // coalesced
        }
    }
    STAGE_SP(Pa1q, Pa2q)
    TRANSPOSE_ER2

    // ---- GEMM3: e @ Wa1[256:384]; m -> At (bf16) -> mPq at recv-sorted slots
    LOAD_AF
#pragma unroll 1
    for (int h = 0; h < 2; ++h) {
        f32x4v acc[4];
#pragma unroll
        for (int n2 = 0; n2 < 4; ++n2) acc[n2] = zz;
#pragma unroll
        for (int n2 = 0; n2 < 4; ++n2)
#pragma unroll
            for (int kc = 0; kc < 4; ++kc)
                acc[n2] = mfma_bf16(af[kc], Bp3[(kc * 8 + h * 4 + n2) * 64 + l], acc[n2]);
        f32x4v scv[4];
#pragma unroll
        for (int n2 = 0; n2 < 4; ++n2)
            scv[n2] = mfma_bf16(afE, W0a[(h * 4 + n2) * 64 + l], zz);
#pragma unroll
        for (int n2 = 0; n2 < 4; ++n2) {
            const int nt = h * 4 + n2;
            const int fo = nt * 16 + c;
            const float bt = ba1[fo];
#pragma unroll
            for (int r = 0; r < 4; ++r) {
                const float p12 = bf2f(sPh[(16 * w + q * 4 + r) * 136 + fo]);
                const float x = acc[n2][r] + bt + p12;
                At[(16 * w + q * 4 + r) * 136 + fo] = f2bf(swishf_(x) * scv[n2][r]);
            }
        }
    }
#pragma unroll
    for (int j = 0; j < 16; ++j) {
        const int ep = epos[wbase + j];
        mPq[(size_t)ep * 64 + l] = At32[(16 * w + j) * 68 + l];  // 256B full-line row
    }
#undef LOAD_AF
#undef TRANSPOSE_ER2
#undef STAGE_SP
}

// dv aggregation (streaming reads: mPq is recv-sorted) fused with v update + vq.
// 4-way unrolled with paired accumulators.
__global__ void k_dvagg(const unsigned int* __restrict__ mPq,
                        const int* __restrict__ startR, const int* __restrict__ cntR,
                        float* __restrict__ v, unsigned int* __restrict__ vq, int N) {
    const int a = blockIdx.x * 4 + (threadIdx.x >> 6);
    if (a >= N) return;
    const int l = threadIdx.x & 63;
    const int s0 = startR[a], n = cntR[a];
    float a0 = 0.0f, a1 = 0.0f, b0 = 0.0f, b1 = 0.0f;
    int i = 0;
    for (; i + 4 <= n; i += 4) {
        const unsigned int u0 = mPq[(size_t)(s0 + i + 0) * 64 + l];
        const unsigned int u1 = mPq[(size_t)(s0 + i + 1) * 64 + l];
        const unsigned int u2 = mPq[(size_t)(s0 + i + 2) * 64 + l];
        const unsigned int u3 = mPq[(size_t)(s0 + i + 3) * 64 + l];
        a0 += blo(u0) + blo(u1);
        a1 += bhi(u0) + bhi(u1);
        b0 += blo(u2) + blo(u3);
        b1 += bhi(u2) + bhi(u3);
    }
    for (; i < n; ++i) {
        const unsigned int u = mPq[(size_t)(s0 + i) * 64 + l];
        a0 += blo(u);
        a1 += bhi(u);
    }
    a0 += b0;
    a1 += b1;
    const float v0 = v[(size_t)a * 128 + 2 * l] + a0;
    const float v1 = v[(size_t)a * 128 + 2 * l + 1] + a1;
    v[(size_t)a * 128 + 2 * l] = v0;
    v[(size_t)a * 128 + 2 * l + 1] = v1;
    vq[(size_t)a * 64 + l] = pk2(v0, v1);
}

__global__ void k_readout(const float* __restrict__ v,
                          const float* __restrict__ W1, const float* __restrict__ b1,
                          const float* __restrict__ W2, const float* __restrict__ b2,
                          const float* __restrict__ W3, const float* __restrict__ b3,
                          float* __restrict__ out) {
    __shared__ float At[128 * 36];
    const int t = threadIdx.x;
    const int tn = t & 31, tm = t >> 5;
    const int f0 = tn << 2;
    const size_t base = (size_t)blockIdx.x * 32;
    {
        const int m = t & 31, cb = t >> 5;
        const float4* src = (const float4*)(v + (base + m) * 128);
#pragma unroll
        for (int i = 0; i < 4; ++i) {
            const int c = cb + (i << 3);
            const float4 ld = src[c];
            float* dst = At + (c << 2) * 32 + m;
            dst[0] = ld.x; dst[32] = ld.y; dst[64] = ld.z; dst[96] = ld.w;
        }
    }
    __syncthreads();
    float4 acc[4] = {};
    gemm32f<32>(At, W1, tm, f0, acc);
    {
        const float4 bv1 = *(const float4*)(b1 + f0);
#pragma unroll
        for (int j = 0; j < 4; ++j) acc[j] = f4swish(f4add(acc[j], bv1));
    }
    __syncthreads();
#pragma unroll
    for (int i = 0; i < 4; ++i) {
        float4 w0;
        w0.x = getc(acc[0], i); w0.y = getc(acc[1], i); w0.z = getc(acc[2], i); w0.w = getc(acc[3], i);
        *(float4*)(At + (f0 + i) * 36 + (tm << 2)) = w0;
    }
    __syncthreads();
    float4 acc2[4] = {};
    gemm32f<36>(At, W2, tm, f0, acc2);
    const float4 bv2 = *(const float4*)(b2 + f0);
    const float4 w3v = *(const float4*)(W3 + f0);
#pragma unroll
    for (int j = 0; j < 4; ++j) {
        const float4 h = f4swish(f4add(acc2[j], bv2));
        float p = h.x * w3v.x + h.y * w3v.y + h.z * w3v.z + h.w * w3v.w;
        p += __shfl_xor(p, 16);
        p += __shfl_xor(p, 8);
        p += __shfl_xor(p, 4);
        p += __shfl_xor(p, 2);
        p += __shfl_xor(p, 1);
        if (tn == 0) out[base + (tm << 2) + j] = p + b3[0];
    }
}

// ---------------------------------------------------------------------------
extern "C" void kernel_launch(void* const* d_in, const int* in_sizes, int n_in,
                              void* d_out, int out_size, void* d_ws, size_t ws_size,
                              hipStream_t stream) {
    const int N = in_sizes[0];
    const int E = in_sizes[2];
    const int A = in_sizes[4];
    const int NG = in_sizes[6];

    const int* an = (const int*)d_in[0];
    const int* ei = (const int*)d_in[1];
    const float* dist = (const float*)d_in[2];
    const int* tb = (const int*)d_in[3];
    const float* rnorm = (const float*)d_in[4];
    const float* cosang = (const float*)d_in[5];
    const int* tnb = (const int*)d_in[6];
    const int* tna = (const int*)d_in[7];
    const float* emb = (const float*)d_in[8];
    const float* Wenc = (const float*)d_in[9];
    const float* benc = (const float*)d_in[10];
    const float* Wang = (const float*)d_in[11];
    const float* Wg = (const float*)d_in[12];
    const float* bg = (const float*)d_in[13];
    const float* Wtb = (const float*)d_in[14];
    const float* btb = (const float*)d_in[15];
    const float* We1 = (const float*)d_in[16];
    const float* be1 = (const float*)d_in[17];
    const float* We0 = (const float*)d_in[18];
    const float* Wa1 = (const float*)d_in[19];
    const float* ba1 = (const float*)d_in[20];
    const float* Wa0 = (const float*)d_in[21];
    const float* W1 = (const float*)d_in[22];
    const float* b1 = (const float*)d_in[23];
    const float* W2 = (const float*)d_in[24];
    const float* b2 = (const float*)d_in[25];
    const float* W3 = (const float*)d_in[26];
    const float* b3 = (const float*)d_in[27];
    float* out = (float*)d_out;

    float* ws = (float*)d_ws;
    size_t off = 0;
    auto alloc = [&](size_t n) { float* p = ws + off; off += (n + 3) & ~(size_t)3; return p; };
    unsigned int* ePq = (unsigned int*)alloc((size_t)E * 64);   // e bf16, slot-major
    unsigned int* mPq = (unsigned int*)alloc((size_t)E * 64);   // m bf16, recv-sorted rows
    float* v_ = alloc((size_t)N * 128);
    unsigned int* vq = (unsigned int*)alloc((size_t)N * 64);    // v bf16-packed
    unsigned int* Gq = (unsigned int*)alloc((size_t)N * 64);    // gate bf16
    unsigned int* Pe1q = (unsigned int*)alloc((size_t)N * 64);
    unsigned int* Pe2q = (unsigned int*)alloc((size_t)N * 64);
    unsigned int* Pa1q = (unsigned int*)alloc((size_t)N * 64);
    unsigned int* Pa2q = (unsigned int*)alloc((size_t)N * 64);
    unsigned int* ef0q = (unsigned int*)alloc((size_t)E * 4);   // ef0 bf16x8 A-frag rows
    unsigned short* angB = (unsigned short*)alloc((size_t)A * 8);   // bf16 ang feats
    unsigned short* angBS = (unsigned short*)alloc((size_t)A * 8);  // bf16, ij-sorted
    int* kat = (int*)alloc((size_t)A);
    int* katS = (int*)alloc((size_t)A);
    int* iij = (int*)alloc((size_t)A);
    int* cnt = (int*)alloc((size_t)E);
    int* start = (int*)alloc((size_t)E);
    int* fill = (int*)alloc((size_t)E);
    int* cntR = (int*)alloc((size_t)N);
    int* startR = (int*)alloc((size_t)N);
    int* fillR = (int*)alloc((size_t)N);
    int* epos = (int*)alloc((size_t)E);
    int* bsum = (int*)alloc(512);
    int* boff = (int*)alloc(256);
    int* acum = boff + 128;
    unsigned short* Bpk = (unsigned short*)alloc((size_t)32 * 8192);  // 32 mats bf16
    unsigned short* Spk = (unsigned short*)alloc((size_t)12 * 2048);  // Wang/We0/Wa0 B-frags

    const int nscanE = (E + 2047) / 2048;
    const int nscanR = (N + 2047) / 2048;

    (void)hipMemsetAsync(cnt, 0, (size_t)E * 4, stream);
    (void)hipMemsetAsync(fill, 0, (size_t)E * 4, stream);
    (void)hipMemsetAsync(cntR, 0, (size_t)N * 4, stream);
    (void)hipMemsetAsync(fillR, 0, (size_t)N * 4, stream);
    k_offsets<<<1, 64, 0, stream>>>(tnb, tna, NG, boff, acum);
    k_angle_setup<<<(A + 255) / 256, 256, 0, stream>>>(tb, rnorm, cosang, ei, E, A, NG,
                                                       boff, acum, angB, kat, iij, cnt);
    // k_edge_init also produces cntR (recv histogram) -> before the N-scan
    k_edge_init<<<E / 16, 512, 0, stream>>>(dist, Wenc, benc, ei, E, cntR, ePq, ef0q);
    k_scan1<<<nscanE, 256, 0, stream>>>(cnt, start, bsum, E);
    k_scan2<<<1, 256, 0, stream>>>(bsum, nscanE);
    k_scan3<<<(E + 255) / 256, 256, 0, stream>>>(start, bsum, E);
    k_scatter<<<(A + 255) / 256, 256, 0, stream>>>(angB, kat, iij, start, fill, angBS, katS, A);
    k_scan1<<<nscanR, 256, 0, stream>>>(cntR, startR, bsum, N);
    k_scan2<<<1, 256, 0, stream>>>(bsum, nscanR);
    k_scan3<<<(N + 255) / 256, 256, 0, stream>>>(startR, bsum, N);
    k_scatter_recv<<<(E + 255) / 256, 256, 0, stream>>>(ei, E, startR, fillR, epos);
    k_pack<<<256, 256, 0, stream>>>(Wg, Wtb, We1, Wa1, Bpk);
    k_pack_s<<<96, 64, 0, stream>>>(Wang, We0, Wa0, Spk);
    k_atom_init<<<(int)(((size_t)N * 64 + 255) / 256), 256, 0, stream>>>(an, emb, v_, vq, N);

    for (int b = 0; b < 4; ++b) {
        k_atom_pre<<<dim3(N / 64, 5), 256, 0, stream>>>(
            vq, Bpk + (size_t)(b * 8) * 16384, bg + b * 128,
            Gq, Pe1q, Pe2q, Pa1q, Pa2q);
        k_edge<<<E / 32, 128, 0, stream>>>(
            angBS, katS, start, cnt, Gq, Spk + (size_t)b * 4096, ef0q,
            ePq, ei, E, Pe1q, Pe2q, Pa1q, Pa2q, epos,
            Bpk + (size_t)(b * 8 + 5) * 16384,
            btb + b * 128, be1 + b * 128,
            Spk + (size_t)(4 + b) * 4096, ba1 + b * 128,
            Spk + (size_t)(8 + b) * 4096, mPq);
        k_dvagg<<<(N + 3) / 4, 256, 0, stream>>>(mPq, startR, cntR, v_, vq, N);
    }
    k_readout<<<N / 32, 256, 0, stream>>>(v_, W1, b1, W2, b2, W3, b3, out);
}

// Round 15
// 951.597 us; speedup vs baseline: 1.4477x; 1.0033x over previous
//
#include <hip/hip_runtime.h>

// ---------------------------------------------------------------------------
// M3GNet forward. N=8000, E=200000, A=400000, NG=100, FD=128.
// R31 = R30 (954.7us best; k_edge frozen) + setup-chain slimming:
//  (1) k_angle_setup+k_scatter merged: tiny k_hist_ang (tb-only) builds the
//      histogram; k_angle_scatter computes features and writes DIRECTLY to
//      the sorted slot. angB/kat/iij buffers deleted (-35MB round trip,
//      -1 launch). Within-segment order nondeterministic, same as before.
//  (2) both k_scan3 launches folded into consumers: bsumE/bsumR persist;
//      k_edge adds bsumE[(e)>>11] at sA0 load; k_scatter_recv/k_dvagg add
//      bsumR[r>>11]. (-2 launches, -1 pass over start.)
// ---------------------------------------------------------------------------

typedef short short8 __attribute__((ext_vector_type(8)));
typedef float f32x4v __attribute__((ext_vector_type(4)));
typedef __bf16 bf16x2_t __attribute__((ext_vector_type(2)));

__device__ __forceinline__ float sigmoidf_(float x) { return 1.0f / (1.0f + __expf(-x)); }
__device__ __forceinline__ float swishf_(float x) { return x * sigmoidf_(x); }

// packed bf16 convert: dst.lo = bf16(a), dst.hi = bf16(b). RNE.
__device__ __forceinline__ unsigned int pk2(float a, float b) {
    bf16x2_t v = {(__bf16)a, (__bf16)b};
    return __builtin_bit_cast(unsigned int, v);
}
__device__ __forceinline__ unsigned short f2bf(float x) {
    return __builtin_bit_cast(unsigned short, (__bf16)x);
}
__device__ __forceinline__ float bf2f(unsigned short u) {
    return __uint_as_float(((unsigned int)u) << 16);
}
__device__ __forceinline__ float blo(unsigned int u) { return __uint_as_float(u << 16); }
__device__ __forceinline__ float bhi(unsigned int u) { return __uint_as_float(u & 0xffff0000u); }
__device__ __forceinline__ unsigned int addbf2(unsigned int a, unsigned int b) {
    return pk2(blo(a) + blo(b), bhi(a) + bhi(b));
}

__device__ __forceinline__ f32x4v mfma_bf16(short8 a, short8 b, f32x4v c) {
    return __builtin_amdgcn_mfma_f32_16x16x32_bf16(a, b, c, 0, 0, 0);
}

__device__ __forceinline__ float4 f4add(float4 a, float4 b) {
    return make_float4(a.x + b.x, a.y + b.y, a.z + b.z, a.w + b.w);
}
__device__ __forceinline__ float4 f4swish(float4 a) {
    return make_float4(swishf_(a.x), swishf_(a.y), swishf_(a.z), swishf_(a.w));
}
__device__ __forceinline__ float getc(const float4& v, int i) {
    return i == 0 ? v.x : (i == 1 ? v.y : (i == 2 ? v.z : v.w));
}

#define FMA4(J, A) \
    acc[J].x = fmaf(A, bv.x, acc[J].x); acc[J].y = fmaf(A, bv.y, acc[J].y); \
    acc[J].z = fmaf(A, bv.z, acc[J].z); acc[J].w = fmaf(A, bv.w, acc[J].w)

template <int S>
__device__ __forceinline__ void gemm32f(const float* As, const float* __restrict__ B,
                                        int tm, int f0, float4 acc[4]) {
#pragma unroll 4
    for (int k = 0; k < 128; ++k) {
        const float4 a0 = *(const float4*)(As + k * S + (tm << 2));
        const float4 bv = *(const float4*)(B + (k << 7) + f0);
        FMA4(0, a0.x); FMA4(1, a0.y); FMA4(2, a0.z); FMA4(3, a0.w);
    }
}

// ---------------------------------------------------------------------------
__global__ void k_offsets(const int* __restrict__ tnb, const int* __restrict__ tna,
                          int NG, int* __restrict__ boff, int* __restrict__ acum) {
    if (threadIdx.x == 0 && blockIdx.x == 0) {
        int ab = 0, aa = 0;
        for (int g = 0; g < NG; ++g) {
            boff[g] = ab;
            ab += tnb[g];
            aa += tna[g];
            acum[g] = aa;
        }
    }
}

// pass 1: angle->edge histogram only (reads tb col 0; no trig, no feature IO)
__global__ void k_hist_ang(const int* __restrict__ tb,
                           const int* __restrict__ boff, const int* __restrict__ acum,
                           int A, int NG, int* __restrict__ cnt) {
    const int a = blockIdx.x * 256 + threadIdx.x;
    if (a >= A) return;
    int lo = 0, hi = NG - 1;
    while (lo < hi) {
        const int mid = (lo + hi) >> 1;
        if (a < acum[mid]) hi = mid; else lo = mid + 1;
    }
    atomicAdd(&cnt[tb[2 * a] + boff[lo]], 1);
}

// pass 2: compute bf16 angle features and scatter DIRECTLY to sorted slot.
__global__ void k_angle_scatter(const int* __restrict__ tb, const float* __restrict__ rnorm,
                                const float* __restrict__ cosang, const int* __restrict__ ei,
                                int E, int A, int NG,
                                const int* __restrict__ boff, const int* __restrict__ acum,
                                const int* __restrict__ start, const int* __restrict__ bsumE,
                                int* __restrict__ fill,
                                unsigned short* __restrict__ angS,
                                int* __restrict__ katS) {
    const int a = blockIdx.x * 256 + threadIdx.x;
    if (a >= A) return;
    int lo = 0, hi = NG - 1;
    while (lo < hi) {
        const int mid = (lo + hi) >> 1;
        if (a < acum[mid]) hi = mid; else lo = mid + 1;
    }
    const int off = boff[lo];
    const int ij = tb[2 * a] + off;
    const int kat = ei[(size_t)E + tb[2 * a + 1] + off];
    const int pos = start[ij] + bsumE[ij >> 11] + atomicAdd(&fill[ij], 1);

    const float r = rnorm[a], c = cosang[a];
    const float rinv = 1.0f / r;
    const float x = r * 0.25f;
    const float fc = 1.0f + x * x * x * (-10.0f + x * (15.0f - 6.0f * x));
    const float fc2 = fc * fc;
    const float p2 = 1.5f * c * c - 0.5f;
    const float p3 = 2.5f * c * c * c - 1.5f * c;
    union { unsigned int ui[8]; uint4 v[2]; } pkk;
#pragma unroll
    for (int n = 0; n < 4; ++n) {
        const float rad = __sinf(r * (float)(n + 1) * 0.7853981633974483f) * rinv * fc2;
        pkk.ui[n * 2 + 0] = pk2(rad, rad * c);
        pkk.ui[n * 2 + 1] = pk2(rad * p2, rad * p3);
    }
    uint4* dst = (uint4*)(angS + (size_t)pos * 16);
    dst[0] = pkk.v[0];
    dst[1] = pkk.v[1];
    katS[pos] = kat;
}

__global__ void k_scan1(const int* __restrict__ cnt, int* __restrict__ start,
                        int* __restrict__ bsum, int n) {
    __shared__ int sh[256];
    const int t = threadIdx.x;
    const int base = blockIdx.x * 2048 + t * 8;
    int v[8], s = 0;
#pragma unroll
    for (int i = 0; i < 8; ++i) { v[i] = (base + i < n) ? cnt[base + i] : 0; s += v[i]; }
    sh[t] = s;
    __syncthreads();
    for (int off = 1; off < 256; off <<= 1) {
        int x = (t >= off) ? sh[t - off] : 0;
        __syncthreads();
        sh[t] += x;
        __syncthreads();
    }
    if (t == 255) bsum[blockIdx.x] = sh[255];
    int run = sh[t] - s;
#pragma unroll
    for (int i = 0; i < 8; ++i) { if (base + i < n) start[base + i] = run; run += v[i]; }
}

__global__ void k_scan2(int* __restrict__ bsum, int nb) {
    __shared__ int sh[256];
    const int t = threadIdx.x;
    int v = (t < nb) ? bsum[t] : 0;
    sh[t] = v;
    __syncthreads();
    for (int off = 1; off < 256; off <<= 1) {
        int x = (t >= off) ? sh[t - off] : 0;
        __syncthreads();
        sh[t] += x;
        __syncthreads();
    }
    if (t < nb) bsum[t] = sh[t] - v;
}

__global__ void k_scatter_recv(const int* __restrict__ ei, int E,
                               const int* __restrict__ startR, const int* __restrict__ bsumR,
                               int* __restrict__ fillR,
                               int* __restrict__ epos) {
    const int e = blockIdx.x * 256 + threadIdx.x;
    if (e < E) {
        const int r = ei[(size_t)E + e];
        epos[e] = startR[r] + bsumR[r >> 11] + atomicAdd(&fillR[r], 1);
    }
}

// pack 32 weight matrices into MFMA B-frag layout (bf16).
// mat = b*8 + {0:Wg, 1:We1a, 2:We1b, 3:Wa1a, 4:Wa1b, 5:Wtb, 6:We1c, 7:Wa1c}
__global__ void k_pack(const float* __restrict__ Wg, const float* __restrict__ Wtb,
                       const float* __restrict__ We1, const float* __restrict__ Wa1,
                       unsigned short* __restrict__ Bpk) {
    const int gid = blockIdx.x * 256 + threadIdx.x;  // 0..65535
    const int mat = gid >> 11;
    const int t2 = gid & 2047;
    const int b = mat >> 3, which = mat & 7;
    const float* W;
    switch (which) {
        case 0: W = Wg + (size_t)b * 16384; break;
        case 1: W = We1 + (size_t)b * 49152; break;
        case 2: W = We1 + (size_t)b * 49152 + 16384; break;
        case 3: W = Wa1 + (size_t)b * 49152; break;
        case 4: W = Wa1 + (size_t)b * 49152 + 16384; break;
        case 5: W = Wtb + (size_t)b * 16384; break;
        case 6: W = We1 + (size_t)b * 49152 + 32768; break;
        default: W = Wa1 + (size_t)b * 49152 + 32768; break;
    }
    const int kc = t2 >> 9, nt = (t2 >> 6) & 7, lane = t2 & 63;
    const int q = lane >> 4, cc = lane & 15;
    const int col = nt * 16 + cc;
    union { unsigned short us[8]; uint4 v; } pk;
#pragma unroll
    for (int j = 0; j < 8; ++j)
        pk.us[j] = f2bf(W[(size_t)(kc * 32 + q * 8 + j) * 128 + col]);
    *(uint4*)(Bpk + (size_t)mat * 16384 + (size_t)((kc * 8 + nt) * 64 + lane) * 8) = pk.v;
}

// pack small-K matrices into MFMA B-frag layout (K padded to 32 with 0).
// m = type*4 + b; type 0: Wang (K=16), type 1: We0 (K=5), type 2: Wa0 (K=5).
__global__ void k_pack_s(const float* __restrict__ Wang, const float* __restrict__ We0g,
                         const float* __restrict__ Wa0g, unsigned short* __restrict__ Spk) {
    const int gid = blockIdx.x * 64 + threadIdx.x;  // 12 mats * 512 lanes
    const int m = gid >> 9;
    const int nt = (gid >> 6) & 7, lane = gid & 63;
    const int b = m & 3, type = m >> 2;
    const int q = lane >> 4, cc = lane & 15;
    const int col = nt * 16 + cc;
    const float* W;
    int K;
    if (type == 0)      { W = Wang + (size_t)b * 2048; K = 16; }
    else if (type == 1) { W = We0g + (size_t)b * 640;  K = 5;  }
    else                { W = Wa0g + (size_t)b * 640;  K = 5;  }
    union { unsigned short us[8]; uint4 v; } pk;
#pragma unroll
    for (int j = 0; j < 8; ++j) {
        const int k = q * 8 + j;
        pk.us[j] = (k < K) ? f2bf(W[(size_t)k * 128 + col]) : (unsigned short)0;
    }
    *(uint4*)(Spk + (size_t)m * 4096 + (size_t)(nt * 64 + lane) * 8) = pk.v;
}

// e init, slot-major layout: ePq[(strip*16 + s)*64 + lane], s = nt*2 + half.
// Also folds the recv-degree histogram and writes ef0q (A-frag-ready bf16x8:
// 5 rbf values + 3 zeros per edge).
__global__ void k_edge_init(const float* __restrict__ dist, const float* __restrict__ Wenc,
                            const float* __restrict__ benc,
                            const int* __restrict__ ei, int E, int* __restrict__ cntR,
                            unsigned int* __restrict__ ePq,
                            unsigned int* __restrict__ ef0q) {
    __shared__ float sarr[16][5];
    const int s = blockIdx.x, t = threadIdx.x;
    if (t < 16) {
        const float r = dist[s * 16 + t];
        const float rinv = 1.0f / r;
        float vv[5];
#pragma unroll
        for (int n = 0; n < 5; ++n) {
            vv[n] = 0.6324555320336759f * __sinf(r * (float)(n + 1) * 0.6283185307179586f) * rinv;
            sarr[t][n] = vv[n];
        }
        uint4 pq;
        pq.x = pk2(vv[0], vv[1]);
        pq.y = pk2(vv[2], vv[3]);
        pq.z = pk2(vv[4], 0.0f);
        pq.w = 0u;
        *(uint4*)(ef0q + (size_t)(s * 16 + t) * 4) = pq;
        atomicAdd(&cntR[ei[(size_t)E + s * 16 + t]], 1);
    }
    __syncthreads();
    const int lane = t >> 3, nt = t & 7;
    const int q = lane >> 4;
    const int f = nt * 16 + (lane & 15);
    float wv[5];
#pragma unroll
    for (int n = 0; n < 5; ++n) wv[n] = Wenc[n * 128 + f];
    const float bz = benc[f];
    float o[4];
#pragma unroll
    for (int r = 0; r < 4; ++r) {
        const int m = q * 4 + r;
        float acc = bz;
#pragma unroll
        for (int n = 0; n < 5; ++n) acc = fmaf(sarr[m][n], wv[n], acc);
        o[r] = swishf_(acc);
    }
    unsigned int* epB = ePq + (size_t)s * 1024;
    epB[(nt * 2) * 64 + lane] = pk2(o[0], o[1]);
    epB[(nt * 2 + 1) * 64 + lane] = pk2(o[2], o[3]);
}

// atom init: v fp32 + vq bf16-packed (lane j holds features 2j,2j+1)
__global__ void k_atom_init(const int* __restrict__ an, const float* __restrict__ emb,
                            float* __restrict__ v, unsigned int* __restrict__ vq, int N) {
    const size_t gid = (size_t)blockIdx.x * 256 + threadIdx.x;
    if (gid >= (size_t)N * 64) return;
    const int a = (int)(gid >> 6), j = (int)(gid & 63);
    const float2 e = *(const float2*)(emb + (size_t)an[a] * 128 + 2 * j);
    *(float2*)(v + (size_t)a * 128 + 2 * j) = e;
    vq[gid] = pk2(e.x, e.y);
}

// ---------------------------------------------------------------------------
// MFMA per-atom GEMMs: 64 atoms/block, wave w owns atoms 16w..16w+15.
// blockIdx.y = g selects the matrix (625 blocks/dispatch keeps all CUs busy).
__global__ void __launch_bounds__(256, 4) k_atom_pre(
    const unsigned int* __restrict__ vq,
    const unsigned short* __restrict__ Bpk5, const float* __restrict__ bg,
    unsigned int* __restrict__ Gq, unsigned int* __restrict__ Pe1q,
    unsigned int* __restrict__ Pe2q,
    unsigned int* __restrict__ Pa1q, unsigned int* __restrict__ Pa2q) {
    __shared__ __align__(16) unsigned short At[64 * 136];
    unsigned int* At32 = (unsigned int*)At;
    const int t = threadIdx.x;
    const int w = t >> 6, l = t & 63;
    const int q = l >> 4, c = l & 15;
    const int g = blockIdx.y;
    const int abase = blockIdx.x * 64 + 16 * w;

    const unsigned short* vh = (const unsigned short*)vq;
    short8 af[4];
#pragma unroll
    for (int kc = 0; kc < 4; ++kc)
        af[kc] = *(const short8*)(vh + (size_t)(abase + c) * 128 + kc * 32 + q * 8);

    const short8* Bp = (const short8*)(Bpk5 + (size_t)g * 16384);
    const f32x4v zz = {0.0f, 0.0f, 0.0f, 0.0f};
    f32x4v acc[8];
#pragma unroll
    for (int nt = 0; nt < 8; ++nt) acc[nt] = zz;
#pragma unroll
    for (int nt = 0; nt < 8; ++nt)
#pragma unroll
        for (int kc = 0; kc < 4; ++kc)
            acc[nt] = mfma_bf16(af[kc], Bp[(kc * 8 + nt) * 64 + l], acc[nt]);

    unsigned int* OUT = (g == 0) ? Gq : (g == 1) ? Pe1q : (g == 2) ? Pe2q
                      : (g == 3) ? Pa1q : Pa2q;
#pragma unroll
    for (int nt = 0; nt < 8; ++nt) {
        const int fo = nt * 16 + c;
        if (g == 0) {
            const float bz = bg[fo];
#pragma unroll
            for (int r = 0; r < 4; ++r)
                At[(16 * w + q * 4 + r) * 136 + fo] = f2bf(sigmoidf_(acc[nt][r] + bz));
        } else {
#pragma unroll
            for (int r = 0; r < 4; ++r)
                At[(16 * w + q * 4 + r) * 136 + fo] = f2bf(acc[nt][r]);
        }
    }
#pragma unroll
    for (int j = 0; j < 16; ++j)
        OUT[(size_t)(abase + j) * 64 + l] = At32[(16 * w + j) * 68 + l];
}

// ---------------------------------------------------------------------------
// Fused per-edge kernel: Phase 0 (MFMA angle batches) + 3 MFMA GEMMs, each
// GEMM computed in two nt-halves (acc[4]) to cut the register peak.
// 128 threads / 2 waves / 32 edges per block. All LDS state is wave-private
// -> NO cross-wave barrier. Type-punned LDS RAW seams ordered by lgkmcnt(0)+
// sched_barrier fences (R17 lesson). sc factors via MFMA (R27).
// startA is the PARTIAL scan; bsumE[(e)>>11] added at sA0 load (R31).
__global__ void __launch_bounds__(128, 4) k_edge(
    const unsigned short* __restrict__ angBS, const int* __restrict__ katS,
    const int* __restrict__ startA, const int* __restrict__ bsumE,
    const int* __restrict__ cntA,
    const unsigned int* __restrict__ Gq, const unsigned short* __restrict__ Wangpk,
    const unsigned int* __restrict__ ef0q,
    unsigned int* __restrict__ ePq, const int* __restrict__ ei, int E,
    const unsigned int* __restrict__ Pe1q, const unsigned int* __restrict__ Pe2q,
    const unsigned int* __restrict__ Pa1q, const unsigned int* __restrict__ Pa2q,
    const int* __restrict__ epos,
    const unsigned short* __restrict__ Bpk3,
    const float* __restrict__ btb, const float* __restrict__ be1,
    const unsigned short* __restrict__ We0pk, const float* __restrict__ ba1,
    const unsigned short* __restrict__ Wa0pk, unsigned int* __restrict__ mPq) {
    __shared__ __align__(16) unsigned short At[32 * 136];
    __shared__ __align__(16) unsigned short sPh[32 * 136];
    __shared__ int sA0[32], sAn[32];
    unsigned int* At32 = (unsigned int*)At;
    unsigned int* sP32 = (unsigned int*)sPh;

    const int t = threadIdx.x;
    const int w = t >> 6, l = t & 63;
    const int q = l >> 4, c = l & 15;
    const int g4 = l >> 4, l16 = l & 15;
    const size_t base = (size_t)blockIdx.x * 32;
    const int wbase = (int)base + 16 * w;
    const f32x4v zz = {0.0f, 0.0f, 0.0f, 0.0f};

    if (l < 16) {
        const int e = wbase + l;
        sA0[16 * w + l] = startA[e] + bsumE[e >> 11];
        sAn[16 * w + l] = cntA[e];
    }

    // prefetch this lane's edge-index rows (feeds STAGE_SP gather addresses)
    int eiS[4], eiR[4];
#pragma unroll
    for (int i = 0; i < 4; ++i) {
        eiS[i] = ei[wbase + i * 4 + g4];
        eiR[i] = ei[(size_t)E + wbase + i * 4 + g4];
    }

    // A-frag of ef0 (row = edge wbase+c, K=5 padded): q==0 lanes hold the 5
    // bf16 rbf values (+3 zeros); q>=1 lanes are zero.
    short8 afE = {0, 0, 0, 0, 0, 0, 0, 0};
    if (q == 0)
        afE = *(const short8*)((const unsigned short*)ef0q + (size_t)(wbase + c) * 8);

#define STAGE_SP(P1, P2)                                                         \
    _Pragma("unroll") for (int i = 0; i < 4; ++i) {                              \
        const int j = i * 4 + g4;                                                \
        const uint4 u1 = *(const uint4*)((P1) + (size_t)eiS[i] * 64 + l16 * 4);  \
        const uint4 u2 = *(const uint4*)((P2) + (size_t)eiR[i] * 64 + l16 * 4);  \
        uint4 o;                                                                 \
        o.x = addbf2(u1.x, u2.x); o.y = addbf2(u1.y, u2.y);                      \
        o.z = addbf2(u1.z, u2.z); o.w = addbf2(u1.w, u2.w);                      \
        *(uint4*)(sP32 + (16 * w + j) * 68 + l16 * 4) = o;                       \
    }

    unsigned int* epB = ePq + (size_t)(blockIdx.x * 2 + w) * 1024;  // slot-major

    // ---- Phase 0: MFMA angle projection, 16-angle batches through sPh slab.
    {
        int j = 0;
        const int aBeg = __builtin_amdgcn_readfirstlane(sA0[16 * w]);
        const int aEnd = __builtin_amdgcn_readfirstlane(sA0[16 * w + 15] + sAn[16 * w + 15]);
        int nextB = __builtin_amdgcn_readfirstlane(sA0[16 * w] + sAn[16 * w]);
        float aa0 = 0.0f, aa1 = 0.0f;
        const short8* WB = (const short8*)Wangpk;
        unsigned short* msg = sPh + (16 * w) * 136;
        unsigned int* msg32 = sP32 + (16 * w) * 68;

#define FLUSH_TO(AIDX)                                                           \
        while ((AIDX) >= nextB && j < 15) {                                      \
            At32[(16 * w + j) * 68 + l] = pk2(aa0, aa1);                         \
            aa0 = 0.0f; aa1 = 0.0f;                                              \
            ++j;                                                                 \
            nextB = __builtin_amdgcn_readfirstlane(sA0[16 * w + j] + sAn[16 * w + j]); \
        }

        // prologue: prefetch first batch's A-frag
        short8 afN = {0, 0, 0, 0, 0, 0, 0, 0};
        if (aBeg < aEnd && q < 2 && aBeg + c < aEnd)
            afN = *(const short8*)(angBS + (size_t)(aBeg + c) * 16 + q * 8);

        for (int a0 = aBeg; a0 < aEnd; a0 += 16) {
            const short8 afA = afN;
            // prefetch next batch's A-frag (lands during this batch's work)
            short8 afZ = {0, 0, 0, 0, 0, 0, 0, 0};
            afN = afZ;
            if (q < 2 && a0 + 16 + c < aEnd)
                afN = *(const short8*)(angBS + (size_t)(a0 + 16 + c) * 16 + q * 8);

            // uniform clamped kat loads + all 16 gate gathers, issued before
            // the MFMA/fence region (independent; land by flush time).
            unsigned int gvv[16];
#pragma unroll
            for (int r16 = 0; r16 < 16; ++r16) {
                const int aa = (a0 + r16 < aEnd) ? a0 + r16 : aEnd - 1;
                gvv[r16] = Gq[(size_t)katS[aa] * 64 + l];
            }

#pragma unroll
            for (int nt = 0; nt < 8; ++nt) {
                f32x4v d = mfma_bf16(afA, WB[nt * 64 + l], zz);
#pragma unroll
                for (int r = 0; r < 4; ++r)
                    msg[(q * 4 + r) * 136 + nt * 16 + c] = f2bf(d[r]);
            }
            // Fence 1: all lanes' msg stores complete before cross-lane reads.
            asm volatile("s_waitcnt lgkmcnt(0)" ::: "memory");
            __builtin_amdgcn_sched_barrier(0);

            unsigned int mvv[16];
#pragma unroll
            for (int r16 = 0; r16 < 16; ++r16) mvv[r16] = msg32[r16 * 68 + l];
            // Fence 2: reads drained before next batch's stores overwrite msg.
            asm volatile("s_waitcnt lgkmcnt(0)" ::: "memory");
            __builtin_amdgcn_sched_barrier(0);

#pragma unroll
            for (int r16 = 0; r16 < 16; ++r16) {
                const int a = a0 + r16;
                FLUSH_TO(a)
                aa0 = fmaf(blo(mvv[r16]), blo(gvv[r16]), aa0);
                aa1 = fmaf(bhi(mvv[r16]), bhi(gvv[r16]), aa1);
            }
        }
        At32[(16 * w + j) * 68 + l] = pk2(aa0, aa1);
        for (int jj = j + 1; jj < 16; ++jj) At32[(16 * w + jj) * 68 + l] = 0u;
#undef FLUSH_TO
    }
    // Fence A: At32 (uint) writes of Phase 0 must be LDS-complete and not
    // reorderable vs the short8 LOAD_AF reads below (type-punned RAW).
    // Placed BEFORE STAGE_SP so the Pe gathers stay in flight across GEMM1.
    asm volatile("s_waitcnt lgkmcnt(0)" ::: "memory");
    __builtin_amdgcn_sched_barrier(0);

    // stage Pe sums into the now-free sPh slab (consumed in GEMM2 epilogue;
    // gathers overlap GEMM1). Wave-private.
    STAGE_SP(Pe1q, Pe2q)

    const short8* Bp1 = (const short8*)Bpk3;
    const short8* Bp2 = Bp1 + 2048;
    const short8* Bp3 = Bp2 + 2048;
    const short8* W0e = (const short8*)We0pk;
    const short8* W0a = (const short8*)Wa0pk;

    short8 af[4];
#define LOAD_AF                                                                  \
    _Pragma("unroll") for (int kc = 0; kc < 4; ++kc)                             \
        af[kc] = *(const short8*)(At + (16 * w + c) * 136 + kc * 32 + q * 8);
// transpose from packed er2: row=edge (q*4+r), col=feature (nt*16+c)
#define TRANSPOSE_ER2                                                            \
    _Pragma("unroll") for (int nt = 0; nt < 8; ++nt) {                           \
        At[(16 * w + q * 4 + 0) * 136 + nt * 16 + c] = (unsigned short)er2[2 * nt];        \
        At[(16 * w + q * 4 + 1) * 136 + nt * 16 + c] = (unsigned short)(er2[2 * nt] >> 16);\
        At[(16 * w + q * 4 + 2) * 136 + nt * 16 + c] = (unsigned short)er2[2 * nt + 1];    \
        At[(16 * w + q * 4 + 3) * 136 + nt * 16 + c] = (unsigned short)(er2[2 * nt + 1] >> 16);\
    }

    unsigned int er2[16];

    // ---- GEMM1: agg @ Wtb; e += swish(. + btb)  (two nt-halves, acc[4])
    LOAD_AF
#pragma unroll 1
    for (int h = 0; h < 2; ++h) {
        // prefetch this half's e-old rows before the MFMAs (static indices)
        unsigned int eold[8];
#pragma unroll
        for (int s = 0; s < 8; ++s) eold[s] = epB[(h * 8 + s) * 64 + l];
        f32x4v acc[4];
#pragma unroll
        for (int n2 = 0; n2 < 4; ++n2) acc[n2] = zz;
#pragma unroll
        for (int n2 = 0; n2 < 4; ++n2)
#pragma unroll
            for (int kc = 0; kc < 4; ++kc)
                acc[n2] = mfma_bf16(af[kc], Bp1[(kc * 8 + h * 4 + n2) * 64 + l], acc[n2]);
#pragma unroll
        for (int n2 = 0; n2 < 4; ++n2) {
            const int nt = h * 4 + n2;
            const unsigned int e0 = eold[2 * n2];
            const unsigned int e1 = eold[2 * n2 + 1];
            const float bt = btb[nt * 16 + c];
            er2[2 * nt] = pk2(blo(e0) + swishf_(acc[n2][0] + bt),
                              bhi(e0) + swishf_(acc[n2][1] + bt));
            er2[2 * nt + 1] = pk2(blo(e1) + swishf_(acc[n2][2] + bt),
                                  bhi(e1) + swishf_(acc[n2][3] + bt));
        }
    }
    TRANSPOSE_ER2   // wave-private slab

    // Fence B: orders (a) TRANSPOSE_ER2's ushort At writes vs GEMM2's short8
    // LOAD_AF reads and (b) STAGE_SP(Pe)'s uint4 sPh writes vs GEMM2's ushort
    // sPh reads. Pe gathers are long done (a full GEMM elapsed).
    asm volatile("s_waitcnt lgkmcnt(0)" ::: "memory");
    __builtin_amdgcn_sched_barrier(0);

    // ---- GEMM2: e @ We1[256:384]; e += swish(. + be1 + Psum) * (ef0@We0)
    LOAD_AF
#pragma unroll 1
    for (int h = 0; h < 2; ++h) {
        f32x4v acc[4];
#pragma unroll
        for (int n2 = 0; n2 < 4; ++n2) acc[n2] = zz;
#pragma unroll
        for (int n2 = 0; n2 < 4; ++n2)
#pragma unroll
            for (int kc = 0; kc < 4; ++kc)
                acc[n2] = mfma_bf16(af[kc], Bp2[(kc * 8 + h * 4 + n2) * 64 + l], acc[n2]);
        // sc = ef0 @ We0 via MFMA; D(row=q*4+r, col=nt*16+c) matches use.
        f32x4v scv[4];
#pragma unroll
        for (int n2 = 0; n2 < 4; ++n2)
            scv[n2] = mfma_bf16(afE, W0e[(h * 4 + n2) * 64 + l], zz);
#pragma unroll
        for (int n2 = 0; n2 < 4; ++n2) {
            const int nt = h * 4 + n2;
            const int fo = nt * 16 + c;
            const float bt = be1[fo];
            float vv[4];
#pragma unroll
            for (int r = 0; r < 4; ++r) {
                const float p12 = bf2f(sPh[(16 * w + q * 4 + r) * 136 + fo]);
                const float x = acc[n2][r] + bt + p12;
                const unsigned int eold = er2[2 * nt + (r >> 1)];
                const float eb = (r & 1) ? bhi(eold) : blo(eold);
                vv[r] = eb + swishf_(x) * scv[n2][r];
            }
            er2[2 * nt] = pk2(vv[0], vv[1]);
            er2[2 * nt + 1] = pk2(vv[2], vv[3]);
            epB[(2 * nt) * 64 + l] = er2[2 * nt];          // coalesced
            epB[(2 * nt + 1) * 64 + l] = er2[2 * nt + 1];  // coalesced
        }
    }
    STAGE_SP(Pa1q, Pa2q)
    TRANSPOSE_ER2

    // ---- GEMM3: e @ Wa1[256:384]; m -> At (bf16) -> mPq at recv-sorted slots
    LOAD_AF
#pragma unroll 1
    for (int h = 0; h < 2; ++h) {
        f32x4v acc[4];
#pragma unroll
        for (int n2 = 0; n2 < 4; ++n2) acc[n2] = zz;
#pragma unroll
        for (int n2 = 0; n2 < 4; ++n2)
#pragma unroll
            for (int kc = 0; kc < 4; ++kc)
                acc[n2] = mfma_bf16(af[kc], Bp3[(kc * 8 + h * 4 + n2) * 64 + l], acc[n2]);
        f32x4v scv[4];
#pragma unroll
        for (int n2 = 0; n2 < 4; ++n2)
            scv[n2] = mfma_bf16(afE, W0a[(h * 4 + n2) * 64 + l], zz);
#pragma unroll
        for (int n2 = 0; n2 < 4; ++n2) {
            const int nt = h * 4 + n2;
            const int fo = nt * 16 + c;
            const float bt = ba1[fo];
#pragma unroll
            for (int r = 0; r < 4; ++r) {
                const float p12 = bf2f(sPh[(16 * w + q * 4 + r) * 136 + fo]);
                const float x = acc[n2][r] + bt + p12;
                At[(16 * w + q * 4 + r) * 136 + fo] = f2bf(swishf_(x) * scv[n2][r]);
            }
        }
    }
#pragma unroll
    for (int j = 0; j < 16; ++j) {
        const int ep = epos[wbase + j];
        mPq[(size_t)ep * 64 + l] = At32[(16 * w + j) * 68 + l];  // 256B full-line row
    }
#undef LOAD_AF
#undef TRANSPOSE_ER2
#undef STAGE_SP
}

// dv aggregation (streaming reads: mPq is recv-sorted) fused with v update + vq.
// 4-way unrolled with paired accumulators. startR partial; bsumR added (R31).
__global__ void k_dvagg(const unsigned int* __restrict__ mPq,
                        const int* __restrict__ startR, const int* __restrict__ bsumR,
                        const int* __restrict__ cntR,
                        float* __restrict__ v, unsigned int* __restrict__ vq, int N) {
    const int a = blockIdx.x * 4 + (threadIdx.x >> 6);
    if (a >= N) return;
    const int l = threadIdx.x & 63;
    const int s0 = startR[a] + bsumR[a >> 11], n = cntR[a];
    float a0 = 0.0f, a1 = 0.0f, b0 = 0.0f, b1 = 0.0f;
    int i = 0;
    for (; i + 4 <= n; i += 4) {
        const unsigned int u0 = mPq[(size_t)(s0 + i + 0) * 64 + l];
        const unsigned int u1 = mPq[(size_t)(s0 + i + 1) * 64 + l];
        const unsigned int u2 = mPq[(size_t)(s0 + i + 2) * 64 + l];
        const unsigned int u3 = mPq[(size_t)(s0 + i + 3) * 64 + l];
        a0 += blo(u0) + blo(u1);
        a1 += bhi(u0) + bhi(u1);
        b0 += blo(u2) + blo(u3);
        b1 += bhi(u2) + bhi(u3);
    }
    for (; i < n; ++i) {
        const unsigned int u = mPq[(size_t)(s0 + i) * 64 + l];
        a0 += blo(u);
        a1 += bhi(u);
    }
    a0 += b0;
    a1 += b1;
    const float v0 = v[(size_t)a * 128 + 2 * l] + a0;
    const float v1 = v[(size_t)a * 128 + 2 * l + 1] + a1;
    v[(size_t)a * 128 + 2 * l] = v0;
    v[(size_t)a * 128 + 2 * l + 1] = v1;
    vq[(size_t)a * 64 + l] = pk2(v0, v1);
}

__global__ void k_readout(const float* __restrict__ v,
                          const float* __restrict__ W1, const float* __restrict__ b1,
                          const float* __restrict__ W2, const float* __restrict__ b2,
                          const float* __restrict__ W3, const float* __restrict__ b3,
                          float* __restrict__ out) {
    __shared__ float At[128 * 36];
    const int t = threadIdx.x;
    const int tn = t & 31, tm = t >> 5;
    const int f0 = tn << 2;
    const size_t base = (size_t)blockIdx.x * 32;
    {
        const int m = t & 31, cb = t >> 5;
        const float4* src = (const float4*)(v + (base + m) * 128);
#pragma unroll
        for (int i = 0; i < 4; ++i) {
            const int c = cb + (i << 3);
            const float4 ld = src[c];
            float* dst = At + (c << 2) * 32 + m;
            dst[0] = ld.x; dst[32] = ld.y; dst[64] = ld.z; dst[96] = ld.w;
        }
    }
    __syncthreads();
    float4 acc[4] = {};
    gemm32f<32>(At, W1, tm, f0, acc);
    {
        const float4 bv1 = *(const float4*)(b1 + f0);
#pragma unroll
        for (int j = 0; j < 4; ++j) acc[j] = f4swish(f4add(acc[j], bv1));
    }
    __syncthreads();
#pragma unroll
    for (int i = 0; i < 4; ++i) {
        float4 w0;
        w0.x = getc(acc[0], i); w0.y = getc(acc[1], i); w0.z = getc(acc[2], i); w0.w = getc(acc[3], i);
        *(float4*)(At + (f0 + i) * 36 + (tm << 2)) = w0;
    }
    __syncthreads();
    float4 acc2[4] = {};
    gemm32f<36>(At, W2, tm, f0, acc2);
    const float4 bv2 = *(const float4*)(b2 + f0);
    const float4 w3v = *(const float4*)(W3 + f0);
#pragma unroll
    for (int j = 0; j < 4; ++j) {
        const float4 h = f4swish(f4add(acc2[j], bv2));
        float p = h.x * w3v.x + h.y * w3v.y + h.z * w3v.z + h.w * w3v.w;
        p += __shfl_xor(p, 16);
        p += __shfl_xor(p, 8);
        p += __shfl_xor(p, 4);
        p += __shfl_xor(p, 2);
        p += __shfl_xor(p, 1);
        if (tn == 0) out[base + (tm << 2) + j] = p + b3[0];
    }
}

// ---------------------------------------------------------------------------
extern "C" void kernel_launch(void* const* d_in, const int* in_sizes, int n_in,
                              void* d_out, int out_size, void* d_ws, size_t ws_size,
                              hipStream_t stream) {
    const int N = in_sizes[0];
    const int E = in_sizes[2];
    const int A = in_sizes[4];
    const int NG = in_sizes[6];

    const int* an = (const int*)d_in[0];
    const int* ei = (const int*)d_in[1];
    const float* dist = (const float*)d_in[2];
    const int* tb = (const int*)d_in[3];
    const float* rnorm = (const float*)d_in[4];
    const float* cosang = (const float*)d_in[5];
    const int* tnb = (const int*)d_in[6];
    const int* tna = (const int*)d_in[7];
    const float* emb = (const float*)d_in[8];
    const float* Wenc = (const float*)d_in[9];
    const float* benc = (const float*)d_in[10];
    const float* Wang = (const float*)d_in[11];
    const float* Wg = (const float*)d_in[12];
    const float* bg = (const float*)d_in[13];
    const float* Wtb = (const float*)d_in[14];
    const float* btb = (const float*)d_in[15];
    const float* We1 = (const float*)d_in[16];
    const float* be1 = (const float*)d_in[17];
    const float* We0 = (const float*)d_in[18];
    const float* Wa1 = (const float*)d_in[19];
    const float* ba1 = (const float*)d_in[20];
    const float* Wa0 = (const float*)d_in[21];
    const float* W1 = (const float*)d_in[22];
    const float* b1 = (const float*)d_in[23];
    const float* W2 = (const float*)d_in[24];
    const float* b2 = (const float*)d_in[25];
    const float* W3 = (const float*)d_in[26];
    const float* b3 = (const float*)d_in[27];
    float* out = (float*)d_out;

    float* ws = (float*)d_ws;
    size_t off = 0;
    auto alloc = [&](size_t n) { float* p = ws + off; off += (n + 3) & ~(size_t)3; return p; };
    unsigned int* ePq = (unsigned int*)alloc((size_t)E * 64);   // e bf16, slot-major
    unsigned int* mPq = (unsigned int*)alloc((size_t)E * 64);   // m bf16, recv-sorted rows
    float* v_ = alloc((size_t)N * 128);
    unsigned int* vq = (unsigned int*)alloc((size_t)N * 64);    // v bf16-packed
    unsigned int* Gq = (unsigned int*)alloc((size_t)N * 64);    // gate bf16
    unsigned int* Pe1q = (unsigned int*)alloc((size_t)N * 64);
    unsigned int* Pe2q = (unsigned int*)alloc((size_t)N * 64);
    unsigned int* Pa1q = (unsigned int*)alloc((size_t)N * 64);
    unsigned int* Pa2q = (unsigned int*)alloc((size_t)N * 64);
    unsigned int* ef0q = (unsigned int*)alloc((size_t)E * 4);   // ef0 bf16x8 A-frag rows
    unsigned short* angBS = (unsigned short*)alloc((size_t)A * 8);  // bf16, ij-sorted
    int* katS = (int*)alloc((size_t)A);
    int* cnt = (int*)alloc((size_t)E);
    int* start = (int*)alloc((size_t)E);
    int* fill = (int*)alloc((size_t)E);
    int* cntR = (int*)alloc((size_t)N);
    int* startR = (int*)alloc((size_t)N);
    int* fillR = (int*)alloc((size_t)N);
    int* epos = (int*)alloc((size_t)E);
    int* bsumE = (int*)alloc(512);
    int* bsumR = (int*)alloc(512);
    int* boff = (int*)alloc(256);
    int* acum = boff + 128;
    unsigned short* Bpk = (unsigned short*)alloc((size_t)32 * 8192);  // 32 mats bf16
    unsigned short* Spk = (unsigned short*)alloc((size_t)12 * 2048);  // Wang/We0/Wa0 B-frags

    const int nscanE = (E + 2047) / 2048;
    const int nscanR = (N + 2047) / 2048;

    (void)hipMemsetAsync(cnt, 0, (size_t)E * 4, stream);
    (void)hipMemsetAsync(fill, 0, (size_t)E * 4, stream);
    (void)hipMemsetAsync(cntR, 0, (size_t)N * 4, stream);
    (void)hipMemsetAsync(fillR, 0, (size_t)N * 4, stream);
    k_offsets<<<1, 64, 0, stream>>>(tnb, tna, NG, boff, acum);
    k_hist_ang<<<(A + 255) / 256, 256, 0, stream>>>(tb, boff, acum, A, NG, cnt);
    // k_edge_init also produces cntR (recv histogram) -> before the N-scan
    k_edge_init<<<E / 16, 512, 0, stream>>>(dist, Wenc, benc, ei, E, cntR, ePq, ef0q);
    k_scan1<<<nscanE, 256, 0, stream>>>(cnt, start, bsumE, E);
    k_scan2<<<1, 256, 0, stream>>>(bsumE, nscanE);
    k_angle_scatter<<<(A + 255) / 256, 256, 0, stream>>>(tb, rnorm, cosang, ei, E, A, NG,
                                                         boff, acum, start, bsumE, fill,
                                                         angBS, katS);
    k_scan1<<<nscanR, 256, 0, stream>>>(cntR, startR, bsumR, N);
    k_scan2<<<1, 256, 0, stream>>>(bsumR, nscanR);
    k_scatter_recv<<<(E + 255) / 256, 256, 0, stream>>>(ei, E, startR, bsumR, fillR, epos);
    k_pack<<<256, 256, 0, stream>>>(Wg, Wtb, We1, Wa1, Bpk);
    k_pack_s<<<96, 64, 0, stream>>>(Wang, We0, Wa0, Spk);
    k_atom_init<<<(int)(((size_t)N * 64 + 255) / 256), 256, 0, stream>>>(an, emb, v_, vq, N);

    for (int b = 0; b < 4; ++b) {
        k_atom_pre<<<dim3(N / 64, 5), 256, 0, stream>>>(
            vq, Bpk + (size_t)(b * 8) * 16384, bg + b * 128,
            Gq, Pe1q, Pe2q, Pa1q, Pa2q);
        k_edge<<<E / 32, 128, 0, stream>>>(
            angBS, katS, start, bsumE, cnt, Gq, Spk + (size_t)b * 4096, ef0q,
            ePq, ei, E, Pe1q, Pe2q, Pa1q, Pa2q, epos,
            Bpk + (size_t)(b * 8 + 5) * 16384,
            btb + b * 128, be1 + b * 128,
            Spk + (size_t)(4 + b) * 4096, ba1 + b * 128,
            Spk + (size_t)(8 + b) * 4096, mPq);
        k_dvagg<<<(N + 3) / 4, 256, 0, stream>>>(mPq, startR, bsumR, cntR, v_, vq, N);
    }
    k_readout<<<N / 32, 256, 0, stream>>>(v_, W1, b1, W2, b2, W3, b3, out);
}